// Round 5
// baseline (2544.777 us; speedup 1.0000x reference)
//
#include <hip/hip_runtime.h>
#include <stdint.h>

#define SEQ 512
#define BATCH 128
#define INDIM 256
#define HID 256
#define CS 512

typedef _Float16 f16;
typedef __attribute__((ext_vector_type(8))) _Float16 f16x8;
typedef __attribute__((ext_vector_type(4))) _Float16 f16x4;
typedef __attribute__((ext_vector_type(4))) float f32x4;

// ws layout:
//   [0,1MB)        wx   : [2][1024 n][256 k] f16   (pre-scaled by gate exp2-factor)
//   [1MB,1MB+8KB)  bias : [2048] f32               (pre-scaled)
//   [4MB,...)      gx   : per dir 128MB: [mt 4096][w 4][g*2+cp 8][lane 64][16B]
#define WX_OFF   0u
#define BIAS_OFF (1u<<20)
#define GX_OFF   (4u<<20)
#define GXD ((size_t)4096 * 32768)   // 128MB per dir

// gate scale: y = s_g * (W z + b); f,i,o: s=-log2e -> sig = rcp(1+exp2(y))
//                                   c:     s=+2log2e -> tanh = 1-2*rcp(exp2(y)+1)
#define SC_SIG (-1.4426950408889634f)
#define SC_TANH (2.8853900817779268f)

__device__ __forceinline__ void load_lds16(const void* g, void* l) {
  __builtin_amdgcn_global_load_lds((const __attribute__((address_space(1))) void*)g,
                                   (__attribute__((address_space(3))) void*)l, 16, 0, 0);
}

// ---------------- kernel 1: Wx -> f16 (pre-scaled), bias table -----------------
struct PrepP { const float* W[8]; const float* Bv[8]; f16* wx; float* bias; };

__global__ __launch_bounds__(256) void k_prep(PrepP p) {
  const int u = blockIdx.x * 256 + threadIdx.x;       // 131072 threads exactly
  const int k4 = (u & 63) * 4;
  const int n = (u >> 6) & 1023;
  const int dir = u >> 16;
  const int g = n >> 8;
  const float s = (g == 2) ? SC_TANH : SC_SIG;
  const float* src = p.W[dir * 4 + g] + (size_t)(n & 255) * CS + HID + k4;
  f32x4 a = *(const f32x4*)src;
  f16x4 v;
  #pragma unroll
  for (int j = 0; j < 4; ++j) v[j] = (f16)(a[j] * s);
  *(f16x4*)(p.wx + ((size_t)dir * 1024 + n) * 256 + k4) = v;
  if (u < 2048) {
    const int gg = (u >> 8) & 3;
    const float ss = (gg == 2) ? SC_TANH : SC_SIG;
    p.bias[u] = p.Bv[(u >> 10) * 4 + gg][u & 255] * ss;
  }
}

// ---------------- kernel 2: Gx = X @ Wx^T + b  (f16, k_rec-DMA layout) ----------
struct GemP { const float* X; const f16* wx; const float* bias; f16* gx; int d0, nd; };

__global__ __launch_bounds__(256) void k_gemm(GemP p) {
  __shared__ float As[128 * 64];   // 32KB, rows 256B, XOR-swizzled
  __shared__ f16   Bs[128 * 64];   // 16KB, rows 128B, XOR-swizzled
  const int tid = threadIdx.x, l = tid & 63, w = tid >> 6;
  const int lp = l & 15, lg = l >> 4;
  const int NB = 8 * p.nd;
  const int nb = blockIdx.x % NB, mb = blockIdx.x / NB;
  const int m0 = mb * 128;
  const int wm = w >> 1, wn = w & 1;

  f32x4 acc[4][4];
  #pragma unroll
  for (int a = 0; a < 4; ++a)
    #pragma unroll
    for (int b = 0; b < 4; ++b) acc[a][b] = (f32x4){0.f, 0.f, 0.f, 0.f};

  auto stage = [&](int kb) {
    #pragma unroll
    for (int j = 0; j < 8; ++j) {
      const int i = w * 8 + j;
      const int rl = i * 4 + lg;
      const int kc = (lp * 16) ^ ((rl & 7) << 4);
      const char* g = (const char*)p.X + ((size_t)(m0 + rl) * 256 + (size_t)kb * 64) * 4 + kc;
      load_lds16(g, (char*)As + i * 1024 + l * 16);
    }
    #pragma unroll
    for (int j = 0; j < 4; ++j) {
      const int i = w * 4 + j;
      const int rl = i * 8 + (l >> 3);
      const int kc = ((l & 7) * 16) ^ ((rl & 7) << 4);
      const char* g = (const char*)p.wx + ((size_t)(p.d0 * 1024 + nb * 128 + rl) * 256 + (size_t)kb * 64) * 2 + kc;
      load_lds16(g, (char*)Bs + i * 1024 + l * 16);
    }
  };

  stage(0);
  for (int kb = 0; kb < 4; ++kb) {
    __syncthreads();
    #pragma unroll
    for (int ks = 0; ks < 2; ++ks) {
      f16x8 af[4];
      #pragma unroll
      for (int mi = 0; mi < 4; ++mi) {
        const int r = wm * 64 + mi * 16 + lp;
        const int kbyte = ks * 128 + lg * 32;
        const int sw = (r & 7) << 4;
        f32x4 a0 = *(const f32x4*)((const char*)As + r * 256 + (kbyte ^ sw));
        f32x4 a1 = *(const f32x4*)((const char*)As + r * 256 + ((kbyte + 16) ^ sw));
        f16x8 v;
        #pragma unroll
        for (int j = 0; j < 4; ++j) { v[j] = (f16)a0[j]; v[4 + j] = (f16)a1[j]; }
        af[mi] = v;
      }
      #pragma unroll
      for (int ni = 0; ni < 4; ++ni) {
        const int rn = wn * 64 + ni * 16 + lp;
        const int kbyte = (ks * 64 + lg * 16) ^ ((rn & 7) << 4);
        f16x8 bf = *(const f16x8*)((const char*)Bs + rn * 128 + kbyte);
        #pragma unroll
        for (int mi = 0; mi < 4; ++mi)
          acc[mi][ni] = __builtin_amdgcn_mfma_f32_16x16x32_f16(af[mi], bf, acc[mi][ni], 0, 0, 0);
      }
    }
    if (kb < 3) { __syncthreads(); stage(kb + 1); }
  }

  // epilogue: +bias, f16, store in k_rec DMA layout
  #pragma unroll
  for (int ni = 0; ni < 4; ++ni) {
    const int n_all = nb * 128 + wn * 64 + ni * 16 + lp;
    const float bv = p.bias[p.d0 * 1024 + n_all];
    const int gdl = n_all >> 10;
    const int n = n_all & 1023;
    const int g = n >> 8, hid = n & 255;
    const int wr = hid >> 6, c = (hid >> 4) & 3;
    #pragma unroll
    for (int mi = 0; mi < 4; ++mi) {
      const int mt = (m0 + wm * 64 + mi * 16) >> 4;
      f16x4 h4;
      #pragma unroll
      for (int r = 0; r < 4; ++r) h4[r] = (f16)(acc[mi][ni][r] + bv);
      char* dst = (char*)p.gx + (size_t)gdl * GXD
                + ((((size_t)mt * 4 + wr) * 8) + g * 2 + (c >> 1)) * 1024
                + (size_t)l * 16 + (c & 1) * 8;
      *(f16x4*)dst = h4;
    }
  }
}

// ---------------- kernel 3: block-local recurrence (no global sync) ------------
// LDS: [0,122880)        wt: wave w at w*30720, 15 lins (all but 11) x 2 k2 x 1KB
//      [122880,139264)   h: 2 buffers x (16 rows x 256 hid f16), byte ^= (row&7)<<4
//      [139264,155648)   gx: wave w at +w*4096, 4 chunks (g) x 64 lanes x 16B
#define WTB_STRIDE 30720
#define HB_OFF  122880
#define GXB_OFF 139264
#define REC_LDS 155648

struct RecP { const float* W[8]; const f16* gx; float* out; int d0; };

__global__ __launch_bounds__(256, 1) void k_rec(RecP p) {
  extern __shared__ char smem[];
  const int tid = threadIdx.x, l = tid & 63, w = tid >> 6;
  const int lp = l & 15, lg = l >> 4;
  const int bx = blockIdx.x;
  const int dirl = bx >> 3;
  const int dir = p.d0 + dirl;
  const int bt = bx & 7;

  char* wtb = smem + w * WTB_STRIDE;
  char* gxb = smem + GXB_OFF + w * 4096;
  const char* gxd = (const char*)p.gx + (size_t)dirl * GXD;

  // ---- weights (pre-scaled per gate): ks<6 + lin11(ks6,7) in regs; 15 lins'
  //      ks 6..7 in LDS ----
  f16x8 Br[4][4][6];
  f16x8 Brx[2];   // lin 11 = (g2,c3), ks 6..7
  #pragma unroll
  for (int g = 0; g < 4; ++g) {
    const float s = (g == 2) ? SC_TANH : SC_SIG;
    #pragma unroll
    for (int c = 0; c < 4; ++c) {
      const float* wr = p.W[dir * 4 + g] + (size_t)(w * 64 + c * 16 + lp) * CS;
      #pragma unroll
      for (int ks = 0; ks < 8; ++ks) {
        f32x4 a0 = *(const f32x4*)(wr + ks * 32 + lg * 8);
        f32x4 a1 = *(const f32x4*)(wr + ks * 32 + lg * 8 + 4);
        f16x8 v;
        #pragma unroll
        for (int j = 0; j < 4; ++j) { v[j] = (f16)(a0[j] * s); v[4 + j] = (f16)(a1[j] * s); }
        const int lin = g * 4 + c;
        if (ks < 6) Br[g][c][ks] = v;
        else if (lin == 11) Brx[ks - 6] = v;
        else {
          const int widx = lin - (lin > 11 ? 1 : 0);
          *(f16x8*)(wtb + (widx * 2 + (ks - 6)) * 1024 + (size_t)l * 16) = v;
        }
      }
    }
  }

  float cst[4][4];
  #pragma unroll
  for (int c = 0; c < 4; ++c)
    #pragma unroll
    for (int r = 0; r < 4; ++r) cst[c][r] = 0.f;

  int tt = dir ? (SEQ - 1) : 0;
  const int stp = dir ? -1 : 1;

  // out addressing: uniform base + 32-bit per-thread offset
  float* outb = p.out + ((size_t)(bt * 16) * 512 + (size_t)dir * 256);
  const int vo = (lg * 4) * 512 + w * 64 + lp;     // dword offset at r=0,c=0

  // half-fill of gx LDS: 4 chunks (one per gate) of chosen cp
  auto fill_gx = [&](int mt, int cp) {
    const char* src = gxd + (((size_t)mt * 4 + w) * 8 + cp) * 1024 + (size_t)l * 16;
    #pragma unroll
    for (int g = 0; g < 4; ++g)
      load_lds16(src + g * 2048, gxb + g * 1024 + (size_t)l * 16);
  };

  fill_gx(tt * 8 + bt, 0);
  asm volatile("s_waitcnt vmcnt(0)" ::: "memory");
  __builtin_amdgcn_sched_barrier(0);
  __builtin_amdgcn_s_barrier();

  for (int t = 0; t < SEQ; ++t, tt += stp) {
    const int pr = ((t & 1) ^ 1) * 8192;   // read h buffer (valid for t>0)
    const int pw = (t & 1) * 8192;         // write h buffer

    f16x8 a[8];
    if (t > 0) {
      #pragma unroll
      for (int ks = 0; ks < 8; ++ks) {
        const int byte = ((lp * 512 + ks * 64 + lg * 16) ^ ((lp & 7) << 4)) + pr;
        a[ks] = *(const f16x8*)(smem + HB_OFF + byte);
      }
    }
    // cp0 fill (issued at c==2 of prev step) landed; <=8 newer out-stores fly
    asm volatile("s_waitcnt vmcnt(8)" ::: "memory");
    __builtin_amdgcn_sched_barrier(0);

    float* outt = outb + (size_t)tt * (128 * 512);
    f16x8 q[4];
    int ttn = tt + stp;
    ttn = ttn < 0 ? 0 : (ttn > SEQ - 1 ? SEQ - 1 : ttn);

    #pragma unroll
    for (int c = 0; c < 4; ++c) {
      if (c == 0) {
        #pragma unroll
        for (int g = 0; g < 4; ++g)
          q[g] = *(const f16x8*)(gxb + g * 1024 + (size_t)l * 16);
        // q reads done -> overwrite gxb with cp1 half of THIS step
        asm volatile("s_waitcnt lgkmcnt(0)" ::: "memory");
        fill_gx(tt * 8 + bt, 1);
        __builtin_amdgcn_sched_barrier(0);
      } else if (c == 2) {
        // cp1 landed (8 newer ops: c0+c1 out-stores)
        asm volatile("s_waitcnt vmcnt(8)" ::: "memory");
        #pragma unroll
        for (int g = 0; g < 4; ++g)
          q[g] = *(const f16x8*)(gxb + g * 1024 + (size_t)l * 16);
        asm volatile("s_waitcnt lgkmcnt(0)" ::: "memory");
        fill_gx(ttn * 8 + bt, 0);   // cp0 of NEXT step
        __builtin_amdgcn_sched_barrier(0);
      }
      f32x4 acc[4];
      #pragma unroll
      for (int g = 0; g < 4; ++g)
        #pragma unroll
        for (int r = 0; r < 4; ++r) acc[g][r] = (float)q[g][(c & 1) * 4 + r];

      if (t > 0) {
        #pragma unroll
        for (int ks = 0; ks < 6; ++ks)
          #pragma unroll
          for (int g = 0; g < 4; ++g)
            acc[g] = __builtin_amdgcn_mfma_f32_16x16x32_f16(a[ks], Br[g][c][ks], acc[g], 0, 0, 0);
        #pragma unroll
        for (int k2 = 0; k2 < 2; ++k2)
          #pragma unroll
          for (int g = 0; g < 4; ++g) {
            const int lin = g * 4 + c;
            f16x8 bv;
            if (lin == 11) bv = Brx[k2];
            else {
              const int widx = lin - (lin > 11 ? 1 : 0);
              bv = *(const f16x8*)(wtb + (widx * 2 + k2) * 1024 + (size_t)l * 16);
            }
            acc[g] = __builtin_amdgcn_mfma_f32_16x16x32_f16(a[6 + k2], bv, acc[g], 0, 0, 0);
          }
      }
      #pragma unroll
      for (int r = 0; r < 4; ++r) {
        // pre-activations arrive exp2-scaled (f,i,o: -log2e ; c: +2log2e)
        const float fg = __builtin_amdgcn_rcpf(1.0f + __builtin_amdgcn_exp2f(acc[0][r]));
        const float ig = __builtin_amdgcn_rcpf(1.0f + __builtin_amdgcn_exp2f(acc[1][r]));
        const float cg = 1.0f - 2.0f * __builtin_amdgcn_rcpf(__builtin_amdgcn_exp2f(acc[2][r]) + 1.0f);
        const float og = __builtin_amdgcn_rcpf(1.0f + __builtin_amdgcn_exp2f(acc[3][r]));
        const float cn = fg * cst[c][r] + ig * cg;
        cst[c][r] = cn;
        const float th = 1.0f - 2.0f * __builtin_amdgcn_rcpf(__builtin_amdgcn_exp2f(cn * SC_TANH) + 1.0f);
        const float h = og * th;
        const int row = lg * 4 + r;
        const int hid = w * 64 + c * 16 + lp;
        const int hbyte = ((row * 512 + hid * 2) ^ ((row & 7) << 4)) + pw;
        *(f16*)(smem + HB_OFF + hbyte) = (f16)h;
        outt[vo + r * 512 + c * 16] = h;
      }
    }

    // h writes visible to all waves before next step's h reads
    asm volatile("s_waitcnt lgkmcnt(0)" ::: "memory");
    __builtin_amdgcn_sched_barrier(0);
    __builtin_amdgcn_s_barrier();
  }
}

// ---------------- launch -------------------------------------------------------
extern "C" void kernel_launch(void* const* d_in, const int* in_sizes, int n_in,
                              void* d_out, int out_size, void* d_ws, size_t ws_size,
                              hipStream_t stream) {
  (void)in_sizes; (void)n_in; (void)out_size;
  PrepP pp;
  const float* X = (const float*)d_in[0];
  for (int i = 0; i < 8; ++i) {
    pp.W[i]  = (const float*)d_in[1 + 2 * i];
    pp.Bv[i] = (const float*)d_in[2 + 2 * i];
  }
  char* ws = (char*)d_ws;
  pp.wx = (f16*)(ws + WX_OFF);
  pp.bias = (float*)(ws + BIAS_OFF);
  f16* gx = (f16*)(ws + GX_OFF);

  int nd;
  if (ws_size >= (size_t)GX_OFF + 2 * GXD) nd = 2;
  else if (ws_size >= (size_t)GX_OFF + GXD) nd = 1;
  else return;

  hipFuncSetAttribute(reinterpret_cast<const void*>(k_rec),
                      hipFuncAttributeMaxDynamicSharedMemorySize, REC_LDS);

  k_prep<<<dim3(512), dim3(256), 0, stream>>>(pp);

  const int passes = (nd == 2) ? 1 : 2;
  for (int ps = 0; ps < passes; ++ps) {
    const int d0 = (nd == 2) ? 0 : ps;
    GemP gp; gp.X = X; gp.wx = pp.wx; gp.bias = pp.bias; gp.gx = gx; gp.d0 = d0; gp.nd = nd;
    k_gemm<<<dim3(512 * 8 * nd), dim3(256), 0, stream>>>(gp);
    RecP rp;
    for (int i = 0; i < 8; ++i) rp.W[i] = pp.W[i];
    rp.gx = gx; rp.out = (float*)d_out; rp.d0 = d0;
    k_rec<<<dim3(8 * nd), dim3(256), REC_LDS, stream>>>(rp);
  }
}

// Round 6
// 2518.845 us; speedup vs baseline: 1.0103x; 1.0103x over previous
//
#include <hip/hip_runtime.h>
#include <stdint.h>

#define SEQ 512
#define BATCH 128
#define INDIM 256
#define HID 256
#define CS 512

typedef _Float16 f16;
typedef __attribute__((ext_vector_type(8))) _Float16 f16x8;
typedef __attribute__((ext_vector_type(4))) _Float16 f16x4;
typedef __attribute__((ext_vector_type(4))) float f32x4;

// ws layout:
//   [0,1MB)        wx   : [2][1024 n][256 k] f16   (pre-scaled by gate exp2-factor)
//   [1MB,1MB+8KB)  bias : [2048] f32               (pre-scaled)
//   [4MB,...)      gx   : per dir 128MB: [mt 4096][w 4][g*2+cp 8][lane 64][16B]
#define WX_OFF   0u
#define BIAS_OFF (1u<<20)
#define GX_OFF   (4u<<20)
#define GXD ((size_t)4096 * 32768)   // 128MB per dir

// gate scale: y = s_g * (W z + b); f,i,o: s=-log2e -> sig = rcp(1+exp2(y))
//                                   c:     s=+2log2e -> tanh = 1-2*rcp(exp2(y)+1)
#define SC_SIG (-1.4426950408889634f)
#define SC_TANH (2.8853900817779268f)

__device__ __forceinline__ void load_lds16(const void* g, void* l) {
  __builtin_amdgcn_global_load_lds((const __attribute__((address_space(1))) void*)g,
                                   (__attribute__((address_space(3))) void*)l, 16, 0, 0);
}

// ---------------- kernel 1: Wx -> f16 (pre-scaled), bias table -----------------
struct PrepP { const float* W[8]; const float* Bv[8]; f16* wx; float* bias; };

__global__ __launch_bounds__(256) void k_prep(PrepP p) {
  const int u = blockIdx.x * 256 + threadIdx.x;       // 131072 threads exactly
  const int k4 = (u & 63) * 4;
  const int n = (u >> 6) & 1023;
  const int dir = u >> 16;
  const int g = n >> 8;
  const float s = (g == 2) ? SC_TANH : SC_SIG;
  const float* src = p.W[dir * 4 + g] + (size_t)(n & 255) * CS + HID + k4;
  f32x4 a = *(const f32x4*)src;
  f16x4 v;
  #pragma unroll
  for (int j = 0; j < 4; ++j) v[j] = (f16)(a[j] * s);
  *(f16x4*)(p.wx + ((size_t)dir * 1024 + n) * 256 + k4) = v;
  if (u < 2048) {
    const int gg = (u >> 8) & 3;
    const float ss = (gg == 2) ? SC_TANH : SC_SIG;
    p.bias[u] = p.Bv[(u >> 10) * 4 + gg][u & 255] * ss;
  }
}

// ---------------- kernel 2: Gx = X @ Wx^T + b  (f16, k_rec-DMA layout) ----------
struct GemP { const float* X; const f16* wx; const float* bias; f16* gx; int d0, nd; };

__global__ __launch_bounds__(256) void k_gemm(GemP p) {
  __shared__ float As[128 * 64];   // 32KB, rows 256B, XOR-swizzled
  __shared__ f16   Bs[128 * 64];   // 16KB, rows 128B, XOR-swizzled
  const int tid = threadIdx.x, l = tid & 63, w = tid >> 6;
  const int lp = l & 15, lg = l >> 4;
  const int NB = 8 * p.nd;
  const int nb = blockIdx.x % NB, mb = blockIdx.x / NB;
  const int m0 = mb * 128;
  const int wm = w >> 1, wn = w & 1;

  f32x4 acc[4][4];
  #pragma unroll
  for (int a = 0; a < 4; ++a)
    #pragma unroll
    for (int b = 0; b < 4; ++b) acc[a][b] = (f32x4){0.f, 0.f, 0.f, 0.f};

  auto stage = [&](int kb) {
    #pragma unroll
    for (int j = 0; j < 8; ++j) {
      const int i = w * 8 + j;
      const int rl = i * 4 + lg;
      const int kc = (lp * 16) ^ ((rl & 7) << 4);
      const char* g = (const char*)p.X + ((size_t)(m0 + rl) * 256 + (size_t)kb * 64) * 4 + kc;
      load_lds16(g, (char*)As + i * 1024 + l * 16);
    }
    #pragma unroll
    for (int j = 0; j < 4; ++j) {
      const int i = w * 4 + j;
      const int rl = i * 8 + (l >> 3);
      const int kc = ((l & 7) * 16) ^ ((rl & 7) << 4);
      const char* g = (const char*)p.wx + ((size_t)(p.d0 * 1024 + nb * 128 + rl) * 256 + (size_t)kb * 64) * 2 + kc;
      load_lds16(g, (char*)Bs + i * 1024 + l * 16);
    }
  };

  stage(0);
  for (int kb = 0; kb < 4; ++kb) {
    __syncthreads();
    #pragma unroll
    for (int ks = 0; ks < 2; ++ks) {
      f16x8 af[4];
      #pragma unroll
      for (int mi = 0; mi < 4; ++mi) {
        const int r = wm * 64 + mi * 16 + lp;
        const int kbyte = ks * 128 + lg * 32;
        const int sw = (r & 7) << 4;
        f32x4 a0 = *(const f32x4*)((const char*)As + r * 256 + (kbyte ^ sw));
        f32x4 a1 = *(const f32x4*)((const char*)As + r * 256 + ((kbyte + 16) ^ sw));
        f16x8 v;
        #pragma unroll
        for (int j = 0; j < 4; ++j) { v[j] = (f16)a0[j]; v[4 + j] = (f16)a1[j]; }
        af[mi] = v;
      }
      #pragma unroll
      for (int ni = 0; ni < 4; ++ni) {
        const int rn = wn * 64 + ni * 16 + lp;
        const int kbyte = (ks * 64 + lg * 16) ^ ((rn & 7) << 4);
        f16x8 bf = *(const f16x8*)((const char*)Bs + rn * 128 + kbyte);
        #pragma unroll
        for (int mi = 0; mi < 4; ++mi)
          acc[mi][ni] = __builtin_amdgcn_mfma_f32_16x16x32_f16(af[mi], bf, acc[mi][ni], 0, 0, 0);
      }
    }
    if (kb < 3) { __syncthreads(); stage(kb + 1); }
  }

  // epilogue: +bias, f16, store in k_rec DMA layout
  #pragma unroll
  for (int ni = 0; ni < 4; ++ni) {
    const int n_all = nb * 128 + wn * 64 + ni * 16 + lp;
    const float bv = p.bias[p.d0 * 1024 + n_all];
    const int gdl = n_all >> 10;
    const int n = n_all & 1023;
    const int g = n >> 8, hid = n & 255;
    const int wr = hid >> 6, c = (hid >> 4) & 3;
    #pragma unroll
    for (int mi = 0; mi < 4; ++mi) {
      const int mt = (m0 + wm * 64 + mi * 16) >> 4;
      f16x4 h4;
      #pragma unroll
      for (int r = 0; r < 4; ++r) h4[r] = (f16)(acc[mi][ni][r] + bv);
      char* dst = (char*)p.gx + (size_t)gdl * GXD
                + ((((size_t)mt * 4 + wr) * 8) + g * 2 + (c >> 1)) * 1024
                + (size_t)l * 16 + (c & 1) * 8;
      *(f16x4*)dst = h4;
    }
  }
}

// ---------------- kernel 3: block-local recurrence (no global sync) ------------
// LDS: [0,106496)        wt: wave w at w*26624, 13 (g,c) pairs x 2 k2 x 1KB
//      [106496,122880)   h: 2 buffers x (16 rows x 256 hid f16), byte ^= (row&7)<<4
//      [122880,155648)   gx: wave w at +w*8192, 8 chunks x 64 lanes x 16B
#define WTB_STRIDE 26624
#define HB_OFF  106496
#define GXB_OFF 122880
#define REC_LDS 155648

struct RecP { const float* W[8]; const f16* gx; float* out; int d0; };

__global__ __launch_bounds__(256, 1) void k_rec(RecP p) {
  extern __shared__ char smem[];
  const int tid = threadIdx.x, l = tid & 63, w = tid >> 6;
  const int lp = l & 15, lg = l >> 4;
  const int bx = blockIdx.x;
  const int dirl = bx >> 3;
  const int dir = p.d0 + dirl;
  const int bt = bx & 7;

  char* wtb = smem + w * WTB_STRIDE;
  char* gxb = smem + GXB_OFF + w * 8192;
  const char* gxd = (const char*)p.gx + (size_t)dirl * GXD;

  // ---- weights (pre-scaled per gate): ks<6 in regs; ks 6..7: lins 11,14,15 in
  //      regs (Brx), the other 13 (g,c) pairs in LDS ----
  f16x8 Br[4][4][6];
  f16x8 Brx[3][2];   // [0]=(g2,c3) lin11, [1]=(g3,c2) lin14, [2]=(g3,c3) lin15
  #pragma unroll
  for (int g = 0; g < 4; ++g) {
    const float s = (g == 2) ? SC_TANH : SC_SIG;
    #pragma unroll
    for (int c = 0; c < 4; ++c) {
      const float* wr = p.W[dir * 4 + g] + (size_t)(w * 64 + c * 16 + lp) * CS;
      #pragma unroll
      for (int ks = 0; ks < 8; ++ks) {
        f32x4 a0 = *(const f32x4*)(wr + ks * 32 + lg * 8);
        f32x4 a1 = *(const f32x4*)(wr + ks * 32 + lg * 8 + 4);
        f16x8 v;
        #pragma unroll
        for (int j = 0; j < 4; ++j) { v[j] = (f16)(a0[j] * s); v[4 + j] = (f16)(a1[j] * s); }
        const int lin = g * 4 + c;
        if (ks < 6) Br[g][c][ks] = v;
        else if (lin == 11) Brx[0][ks - 6] = v;
        else if (lin == 14) Brx[1][ks - 6] = v;
        else if (lin == 15) Brx[2][ks - 6] = v;
        else *(f16x8*)(wtb + ((lin - (lin >= 12 ? 1 : 0)) * 2 + (ks - 6)) * 1024 + (size_t)l * 16) = v;
      }
    }
  }

  float cst[4][4];
  #pragma unroll
  for (int c = 0; c < 4; ++c)
    #pragma unroll
    for (int r = 0; r < 4; ++r) cst[c][r] = 0.f;

  int tt = dir ? (SEQ - 1) : 0;
  const int stp = dir ? -1 : 1;

  // out addressing: uniform base + 32-bit per-thread offset
  float* outb = p.out + ((size_t)(bt * 16) * 512 + (size_t)dir * 256);
  const int vo = (lg * 4) * 512 + w * 64 + lp;     // dword offset at r=0,c=0

  auto issue_gx = [&](int mt) {
    const char* src = gxd + (((size_t)mt * 4 + w) * 8) * 1024 + (size_t)l * 16;
    #pragma unroll
    for (int ch = 0; ch < 8; ++ch)
      load_lds16(src + ch * 1024, gxb + ch * 1024 + (size_t)l * 16);
  };

  issue_gx(tt * 8 + bt);
  asm volatile("s_waitcnt vmcnt(0)" ::: "memory");
  __builtin_amdgcn_sched_barrier(0);
  __builtin_amdgcn_s_barrier();

  for (int t = 0; t < SEQ; ++t, tt += stp) {
    const int pr = ((t & 1) ^ 1) * 8192;   // read h buffer (valid for t>0)
    const int pw = (t & 1) * 8192;         // write h buffer

    f16x8 a[8];
    if (t > 0) {
      #pragma unroll
      for (int ks = 0; ks < 8; ++ks) {
        const int byte = ((lp * 512 + ks * 64 + lg * 16) ^ ((lp & 7) << 4)) + pr;
        a[ks] = *(const f16x8*)(smem + HB_OFF + byte);
      }
    }
    // gx DMA for this step landed; <=4 prior out-stores may still fly
    asm volatile("s_waitcnt vmcnt(4)" ::: "memory");
    __builtin_amdgcn_sched_barrier(0);

    float* outt = outb + (size_t)tt * (128 * 512);

    #pragma unroll
    for (int c = 0; c < 4; ++c) {
      f32x4 acc[4];
      #pragma unroll
      for (int g = 0; g < 4; ++g) {
        f16x4 gv = *(const f16x4*)(gxb + (g * 2 + (c >> 1)) * 1024 + (size_t)l * 16 + (c & 1) * 8);
        #pragma unroll
        for (int r = 0; r < 4; ++r) acc[g][r] = (float)gv[r];
      }
      if (c == 3) {
        // last gxb read done -> drain ds, issue next-step DMA (pinned in place)
        asm volatile("s_waitcnt lgkmcnt(0)" ::: "memory");
        __builtin_amdgcn_sched_barrier(0);
        int ttn = tt + stp;
        ttn = ttn < 0 ? 0 : (ttn > SEQ - 1 ? SEQ - 1 : ttn);
        issue_gx(ttn * 8 + bt);
        asm volatile("" ::: "memory");
        __builtin_amdgcn_sched_barrier(0);
      }
      if (t > 0) {
        #pragma unroll
        for (int ks = 0; ks < 6; ++ks)
          #pragma unroll
          for (int g = 0; g < 4; ++g)
            acc[g] = __builtin_amdgcn_mfma_f32_16x16x32_f16(a[ks], Br[g][c][ks], acc[g], 0, 0, 0);
        #pragma unroll
        for (int k2 = 0; k2 < 2; ++k2)
          #pragma unroll
          for (int g = 0; g < 4; ++g) {
            const int lin = g * 4 + c;
            f16x8 bv;
            if (lin == 11) bv = Brx[0][k2];
            else if (lin == 14) bv = Brx[1][k2];
            else if (lin == 15) bv = Brx[2][k2];
            else bv = *(const f16x8*)(wtb + ((lin - (lin >= 12 ? 1 : 0)) * 2 + k2) * 1024 + (size_t)l * 16);
            acc[g] = __builtin_amdgcn_mfma_f32_16x16x32_f16(a[6 + k2], bv, acc[g], 0, 0, 0);
          }
      }
      #pragma unroll
      for (int r = 0; r < 4; ++r) {
        // pre-activations arrive exp2-scaled (f,i,o: -log2e ; c: +2log2e)
        const float fg = __builtin_amdgcn_rcpf(1.0f + __builtin_amdgcn_exp2f(acc[0][r]));
        const float ig = __builtin_amdgcn_rcpf(1.0f + __builtin_amdgcn_exp2f(acc[1][r]));
        const float cg = 1.0f - 2.0f * __builtin_amdgcn_rcpf(__builtin_amdgcn_exp2f(acc[2][r]) + 1.0f);
        const float og = __builtin_amdgcn_rcpf(1.0f + __builtin_amdgcn_exp2f(acc[3][r]));
        const float cn = fg * cst[c][r] + ig * cg;
        cst[c][r] = cn;
        const float th = 1.0f - 2.0f * __builtin_amdgcn_rcpf(__builtin_amdgcn_exp2f(cn * SC_TANH) + 1.0f);
        const float h = og * th;
        const int row = lg * 4 + r;
        const int hid = w * 64 + c * 16 + lp;
        const int hbyte = ((row * 512 + hid * 2) ^ ((row & 7) << 4)) + pw;
        *(f16*)(smem + HB_OFF + hbyte) = (f16)h;
        outt[vo + r * 512 + c * 16] = h;
      }
    }

    // h writes visible to all waves before next step's h reads
    asm volatile("s_waitcnt lgkmcnt(0)" ::: "memory");
    __builtin_amdgcn_sched_barrier(0);
    __builtin_amdgcn_s_barrier();
  }
}

// ---------------- launch -------------------------------------------------------
extern "C" void kernel_launch(void* const* d_in, const int* in_sizes, int n_in,
                              void* d_out, int out_size, void* d_ws, size_t ws_size,
                              hipStream_t stream) {
  (void)in_sizes; (void)n_in; (void)out_size;
  PrepP pp;
  const float* X = (const float*)d_in[0];
  for (int i = 0; i < 8; ++i) {
    pp.W[i]  = (const float*)d_in[1 + 2 * i];
    pp.Bv[i] = (const float*)d_in[2 + 2 * i];
  }
  char* ws = (char*)d_ws;
  pp.wx = (f16*)(ws + WX_OFF);
  pp.bias = (float*)(ws + BIAS_OFF);
  f16* gx = (f16*)(ws + GX_OFF);

  int nd;
  if (ws_size >= (size_t)GX_OFF + 2 * GXD) nd = 2;
  else if (ws_size >= (size_t)GX_OFF + GXD) nd = 1;
  else return;

  hipFuncSetAttribute(reinterpret_cast<const void*>(k_rec),
                      hipFuncAttributeMaxDynamicSharedMemorySize, REC_LDS);

  k_prep<<<dim3(512), dim3(256), 0, stream>>>(pp);

  const int passes = (nd == 2) ? 1 : 2;
  for (int ps = 0; ps < passes; ++ps) {
    const int d0 = (nd == 2) ? 0 : ps;
    GemP gp; gp.X = X; gp.wx = pp.wx; gp.bias = pp.bias; gp.gx = gx; gp.d0 = d0; gp.nd = nd;
    k_gemm<<<dim3(512 * 8 * nd), dim3(256), 0, stream>>>(gp);
    RecP rp;
    for (int i = 0; i < 8; ++i) rp.W[i] = pp.W[i];
    rp.gx = gx; rp.out = (float*)d_out; rp.d0 = d0;
    k_rec<<<dim3(8 * nd), dim3(256), REC_LDS, stream>>>(rp);
  }
}

// Round 7
// 1908.610 us; speedup vs baseline: 1.3333x; 1.3197x over previous
//
#include <hip/hip_runtime.h>
#include <stdint.h>

#define SEQ 512
#define BATCH 128
#define INDIM 256
#define HID 256
#define CS 512

typedef _Float16 f16;
typedef __attribute__((ext_vector_type(8))) _Float16 f16x8;
typedef __attribute__((ext_vector_type(4))) _Float16 f16x4;
typedef __attribute__((ext_vector_type(4))) float f32x4;

// ws layout:
//   [0,1MB)        wx   : [2][1024 n][256 k] f16   (pre-scaled by gate exp2-factor)
//   [1MB,1MB+8KB)  bias : [2048] f32               (pre-scaled)
//   [4MB,...)      gx   : per dir 128MB: [mt 4096][w 4][g*2+cp 8][lane 64][16B]
#define WX_OFF   0u
#define BIAS_OFF (1u<<20)
#define GX_OFF   (4u<<20)
#define GXD ((size_t)4096 * 32768)   // 128MB per dir

// gate scale: y = s_g * (W z + b); f,i,o: s=-log2e -> sig = rcp(1+exp2(y))
//                                   c:     s=+2log2e -> tanh = 1-2*rcp(exp2(y)+1)
#define SC_SIG (-1.4426950408889634f)
#define SC_TANH (2.8853900817779268f)

__device__ __forceinline__ void load_lds16(const void* g, void* l) {
  __builtin_amdgcn_global_load_lds((const __attribute__((address_space(1))) void*)g,
                                   (__attribute__((address_space(3))) void*)l, 16, 0, 0);
}

// ---------------- kernel 1: Wx -> f16 (pre-scaled), bias table -----------------
struct PrepP { const float* W[8]; const float* Bv[8]; f16* wx; float* bias; };

__global__ __launch_bounds__(256) void k_prep(PrepP p) {
  const int u = blockIdx.x * 256 + threadIdx.x;       // 131072 threads exactly
  const int k4 = (u & 63) * 4;
  const int n = (u >> 6) & 1023;
  const int dir = u >> 16;
  const int g = n >> 8;
  const float s = (g == 2) ? SC_TANH : SC_SIG;
  const float* src = p.W[dir * 4 + g] + (size_t)(n & 255) * CS + HID + k4;
  f32x4 a = *(const f32x4*)src;
  f16x4 v;
  #pragma unroll
  for (int j = 0; j < 4; ++j) v[j] = (f16)(a[j] * s);
  *(f16x4*)(p.wx + ((size_t)dir * 1024 + n) * 256 + k4) = v;
  if (u < 2048) {
    const int gg = (u >> 8) & 3;
    const float ss = (gg == 2) ? SC_TANH : SC_SIG;
    p.bias[u] = p.Bv[(u >> 10) * 4 + gg][u & 255] * ss;
  }
}

// ---------------- kernel 2: Gx = X @ Wx^T + b  (f16, k_rec layout) --------------
struct GemP { const float* X; const f16* wx; const float* bias; f16* gx; int d0, nd; };

__global__ __launch_bounds__(256) void k_gemm(GemP p) {
  __shared__ float As[128 * 64];   // 32KB, rows 256B, XOR-swizzled
  __shared__ f16   Bs[128 * 64];   // 16KB, rows 128B, XOR-swizzled
  const int tid = threadIdx.x, l = tid & 63, w = tid >> 6;
  const int lp = l & 15, lg = l >> 4;
  const int NB = 8 * p.nd;
  const int nb = blockIdx.x % NB, mb = blockIdx.x / NB;
  const int m0 = mb * 128;
  const int wm = w >> 1, wn = w & 1;

  f32x4 acc[4][4];
  #pragma unroll
  for (int a = 0; a < 4; ++a)
    #pragma unroll
    for (int b = 0; b < 4; ++b) acc[a][b] = (f32x4){0.f, 0.f, 0.f, 0.f};

  auto stage = [&](int kb) {
    #pragma unroll
    for (int j = 0; j < 8; ++j) {
      const int i = w * 8 + j;
      const int rl = i * 4 + lg;
      const int kc = (lp * 16) ^ ((rl & 7) << 4);
      const char* g = (const char*)p.X + ((size_t)(m0 + rl) * 256 + (size_t)kb * 64) * 4 + kc;
      load_lds16(g, (char*)As + i * 1024 + l * 16);
    }
    #pragma unroll
    for (int j = 0; j < 4; ++j) {
      const int i = w * 4 + j;
      const int rl = i * 8 + (l >> 3);
      const int kc = ((l & 7) * 16) ^ ((rl & 7) << 4);
      const char* g = (const char*)p.wx + ((size_t)(p.d0 * 1024 + nb * 128 + rl) * 256 + (size_t)kb * 64) * 2 + kc;
      load_lds16(g, (char*)Bs + i * 1024 + l * 16);
    }
  };

  stage(0);
  for (int kb = 0; kb < 4; ++kb) {
    __syncthreads();
    #pragma unroll
    for (int ks = 0; ks < 2; ++ks) {
      f16x8 af[4];
      #pragma unroll
      for (int mi = 0; mi < 4; ++mi) {
        const int r = wm * 64 + mi * 16 + lp;
        const int kbyte = ks * 128 + lg * 32;
        const int sw = (r & 7) << 4;
        f32x4 a0 = *(const f32x4*)((const char*)As + r * 256 + (kbyte ^ sw));
        f32x4 a1 = *(const f32x4*)((const char*)As + r * 256 + ((kbyte + 16) ^ sw));
        f16x8 v;
        #pragma unroll
        for (int j = 0; j < 4; ++j) { v[j] = (f16)a0[j]; v[4 + j] = (f16)a1[j]; }
        af[mi] = v;
      }
      #pragma unroll
      for (int ni = 0; ni < 4; ++ni) {
        const int rn = wn * 64 + ni * 16 + lp;
        const int kbyte = (ks * 64 + lg * 16) ^ ((rn & 7) << 4);
        f16x8 bf = *(const f16x8*)((const char*)Bs + rn * 128 + kbyte);
        #pragma unroll
        for (int mi = 0; mi < 4; ++mi)
          acc[mi][ni] = __builtin_amdgcn_mfma_f32_16x16x32_f16(af[mi], bf, acc[mi][ni], 0, 0, 0);
      }
    }
    if (kb < 3) { __syncthreads(); stage(kb + 1); }
  }

  // epilogue: +bias, f16, store in k_rec layout
  #pragma unroll
  for (int ni = 0; ni < 4; ++ni) {
    const int n_all = nb * 128 + wn * 64 + ni * 16 + lp;
    const float bv = p.bias[p.d0 * 1024 + n_all];
    const int gdl = n_all >> 10;
    const int n = n_all & 1023;
    const int g = n >> 8, hid = n & 255;
    const int wr = hid >> 6, c = (hid >> 4) & 3;
    #pragma unroll
    for (int mi = 0; mi < 4; ++mi) {
      const int mt = (m0 + wm * 64 + mi * 16) >> 4;
      f16x4 h4;
      #pragma unroll
      for (int r = 0; r < 4; ++r) h4[r] = (f16)(acc[mi][ni][r] + bv);
      char* dst = (char*)p.gx + (size_t)gdl * GXD
                + ((((size_t)mt * 4 + wr) * 8) + g * 2 + (c >> 1)) * 1024
                + (size_t)l * 16 + (c & 1) * 8;
      *(f16x4*)dst = h4;
    }
  }
}

// ---------------- kernel 3: block-local recurrence (no global sync) ------------
// LDS: [0,147456)        wt: wave w at w*36864, 36 frags x 1KB:
//                        slots 0..31 = lin*2+(ks-6) for ks in {6,7};
//                        slots 32..35 = ks5 of g=3, c=0..3
//      [147456,163840)   h: 2 buffers x (16 rows x 256 hid f16), byte ^= (row&7)<<4
#define WTB_STRIDE 36864
#define HB_OFF  147456
#define REC_LDS 163840

struct RecP { const float* W[8]; const f16* gx; float* out; int d0; };

__global__ __launch_bounds__(256, 1) void k_rec(RecP p) {
  extern __shared__ char smem[];
  const int tid = threadIdx.x, l = tid & 63, w = tid >> 6;
  const int lp = l & 15, lg = l >> 4;
  const int bx = blockIdx.x;
  const int dirl = bx >> 3;
  const int dir = p.d0 + dirl;
  const int bt = bx & 7;

  char* wtb = smem + w * WTB_STRIDE;
  const char* gxd = (const char*)p.gx + (size_t)dirl * GXD;

  // ---- weights (pre-scaled per gate): regs = ks0-5 for g0-2, ks0-4 for g3;
  //      LDS = ks6,7 all lins + ks5 of g3 ----
  f16x8 Br[4][4][6];   // [3][c][5] never written/read -> DCE'd
  #pragma unroll
  for (int g = 0; g < 4; ++g) {
    const float s = (g == 2) ? SC_TANH : SC_SIG;
    #pragma unroll
    for (int c = 0; c < 4; ++c) {
      const float* wr = p.W[dir * 4 + g] + (size_t)(w * 64 + c * 16 + lp) * CS;
      #pragma unroll
      for (int ks = 0; ks < 8; ++ks) {
        f32x4 a0 = *(const f32x4*)(wr + ks * 32 + lg * 8);
        f32x4 a1 = *(const f32x4*)(wr + ks * 32 + lg * 8 + 4);
        f16x8 v;
        #pragma unroll
        for (int j = 0; j < 4; ++j) { v[j] = (f16)(a0[j] * s); v[4 + j] = (f16)(a1[j] * s); }
        if (ks >= 6)
          *(f16x8*)(wtb + (((g * 4 + c) * 2) + (ks - 6)) * 1024 + (size_t)l * 16) = v;
        else if (ks == 5 && g == 3)
          *(f16x8*)(wtb + (32 + c) * 1024 + (size_t)l * 16) = v;
        else
          Br[g][c][ks] = v;
      }
    }
  }

  float cst[4][4];
  #pragma unroll
  for (int c = 0; c < 4; ++c)
    #pragma unroll
    for (int r = 0; r < 4; ++r) cst[c][r] = 0.f;

  int tt = dir ? (SEQ - 1) : 0;
  const int stp = dir ? -1 : 1;

  // out addressing: uniform base + 32-bit per-thread offset
  float* outb = p.out + ((size_t)(bt * 16) * 512 + (size_t)dir * 256);
  const int vo = (lg * 4) * 512 + w * 64 + lp;     // dword offset at r=0,c=0

  // gx prefetch: q[g][cp] f16x8 in regs, loaded one step ahead
  f16x8 q[4][2];
  auto issue_q = [&](int mt) {
    const char* s = gxd + ((size_t)mt * 4 + w) * 8192 + (size_t)l * 16;
    #pragma unroll
    for (int g = 0; g < 4; ++g)
      #pragma unroll
      for (int cp = 0; cp < 2; ++cp)
        q[g][cp] = *(const f16x8*)(s + (g * 2 + cp) * 1024);
  };

  issue_q(tt * 8 + bt);
  asm volatile("s_waitcnt vmcnt(0) lgkmcnt(0)" ::: "memory");
  __builtin_amdgcn_sched_barrier(0);
  __builtin_amdgcn_s_barrier();

  for (int t = 0; t < SEQ; ++t, tt += stp) {
    const int pr = ((t & 1) ^ 1) * 8192;   // read h buffer (valid for t>0)
    const int pw = (t & 1) * 8192;         // write h buffer

    f16x8 a[8];
    if (t > 0) {
      #pragma unroll
      for (int ks = 0; ks < 8; ++ks) {
        const int byte = ((lp * 512 + ks * 64 + lg * 16) ^ ((lp & 7) << 4)) + pr;
        a[ks] = *(const f16x8*)(smem + HB_OFF + byte);
      }
    }
    // q(t) landed: queue = [12 stores][8 q-loads][4 stores] -> vmcnt(4)
    asm volatile("s_waitcnt vmcnt(4)" ::: "memory");
    __builtin_amdgcn_sched_barrier(0);

    float* outt = outb + (size_t)tt * (128 * 512);
    int ttn = tt + stp;
    ttn = ttn < 0 ? 0 : (ttn > SEQ - 1 ? SEQ - 1 : ttn);

    #pragma unroll
    for (int c = 0; c < 4; ++c) {
      f32x4 acc[4];
      #pragma unroll
      for (int g = 0; g < 4; ++g)
        #pragma unroll
        for (int r = 0; r < 4; ++r) acc[g][r] = (float)q[g][c >> 1][(c & 1) * 4 + r];

      if (c == 3) {
        // old q fully consumed -> prefetch next step's gx (full-step flight)
        issue_q(ttn * 8 + bt);
        __builtin_amdgcn_sched_barrier(0);
      }
      if (t > 0) {
        #pragma unroll
        for (int ks = 0; ks < 6; ++ks)
          #pragma unroll
          for (int g = 0; g < 4; ++g) {
            f16x8 bv;
            if (ks == 5 && g == 3)
              bv = *(const f16x8*)(wtb + (32 + c) * 1024 + (size_t)l * 16);
            else
              bv = Br[g][c][ks];
            acc[g] = __builtin_amdgcn_mfma_f32_16x16x32_f16(a[ks], bv, acc[g], 0, 0, 0);
          }
        #pragma unroll
        for (int k2 = 0; k2 < 2; ++k2)
          #pragma unroll
          for (int g = 0; g < 4; ++g) {
            f16x8 bv = *(const f16x8*)(wtb + (((g * 4 + c) * 2) + k2) * 1024 + (size_t)l * 16);
            acc[g] = __builtin_amdgcn_mfma_f32_16x16x32_f16(a[6 + k2], bv, acc[g], 0, 0, 0);
          }
      }
      #pragma unroll
      for (int r = 0; r < 4; ++r) {
        // pre-activations arrive exp2-scaled (f,i,o: -log2e ; c: +2log2e)
        const float fg = __builtin_amdgcn_rcpf(1.0f + __builtin_amdgcn_exp2f(acc[0][r]));
        const float ig = __builtin_amdgcn_rcpf(1.0f + __builtin_amdgcn_exp2f(acc[1][r]));
        const float cg = 1.0f - 2.0f * __builtin_amdgcn_rcpf(__builtin_amdgcn_exp2f(acc[2][r]) + 1.0f);
        const float og = __builtin_amdgcn_rcpf(1.0f + __builtin_amdgcn_exp2f(acc[3][r]));
        const float cn = fg * cst[c][r] + ig * cg;
        cst[c][r] = cn;
        const float th = 1.0f - 2.0f * __builtin_amdgcn_rcpf(__builtin_amdgcn_exp2f(cn * SC_TANH) + 1.0f);
        const float h = og * th;
        const int row = lg * 4 + r;
        const int hid = w * 64 + c * 16 + lp;
        const int hbyte = ((row * 512 + hid * 2) ^ ((row & 7) << 4)) + pw;
        *(f16*)(smem + HB_OFF + hbyte) = (f16)h;
        outt[vo + r * 512 + c * 16] = h;
      }
    }

    // h writes visible to all waves before next step's h reads
    asm volatile("s_waitcnt lgkmcnt(0)" ::: "memory");
    __builtin_amdgcn_sched_barrier(0);
    __builtin_amdgcn_s_barrier();
  }
}

// ---------------- launch -------------------------------------------------------
extern "C" void kernel_launch(void* const* d_in, const int* in_sizes, int n_in,
                              void* d_out, int out_size, void* d_ws, size_t ws_size,
                              hipStream_t stream) {
  (void)in_sizes; (void)n_in; (void)out_size;
  PrepP pp;
  const float* X = (const float*)d_in[0];
  for (int i = 0; i < 8; ++i) {
    pp.W[i]  = (const float*)d_in[1 + 2 * i];
    pp.Bv[i] = (const float*)d_in[2 + 2 * i];
  }
  char* ws = (char*)d_ws;
  pp.wx = (f16*)(ws + WX_OFF);
  pp.bias = (float*)(ws + BIAS_OFF);
  f16* gx = (f16*)(ws + GX_OFF);

  int nd;
  if (ws_size >= (size_t)GX_OFF + 2 * GXD) nd = 2;
  else if (ws_size >= (size_t)GX_OFF + GXD) nd = 1;
  else return;

  hipFuncSetAttribute(reinterpret_cast<const void*>(k_rec),
                      hipFuncAttributeMaxDynamicSharedMemorySize, REC_LDS);

  k_prep<<<dim3(512), dim3(256), 0, stream>>>(pp);

  const int passes = (nd == 2) ? 1 : 2;
  for (int ps = 0; ps < passes; ++ps) {
    const int d0 = (nd == 2) ? 0 : ps;
    GemP gp; gp.X = X; gp.wx = pp.wx; gp.bias = pp.bias; gp.gx = gx; gp.d0 = d0; gp.nd = nd;
    k_gemm<<<dim3(512 * 8 * nd), dim3(256), 0, stream>>>(gp);
    RecP rp;
    for (int i = 0; i < 8; ++i) rp.W[i] = pp.W[i];
    rp.gx = gx; rp.out = (float*)d_out; rp.d0 = d0;
    k_rec<<<dim3(8 * nd), dim3(256), REC_LDS, stream>>>(rp);
  }
}

// Round 8
// 1536.421 us; speedup vs baseline: 1.6563x; 1.2422x over previous
//
#include <hip/hip_runtime.h>
#include <stdint.h>

#define SEQ 512
#define BATCH 128
#define INDIM 256
#define HID 256
#define CS 512

typedef _Float16 f16;
typedef __attribute__((ext_vector_type(8))) _Float16 f16x8;
typedef __attribute__((ext_vector_type(4))) _Float16 f16x4;
typedef __attribute__((ext_vector_type(4))) float f32x4;

// ws layout:
//   [0,1MB)        wx   : [2][1024 n][256 k] f16   (pre-scaled by gate exp2-factor)
//   [1MB,1MB+8KB)  bias : [2048] f32               (pre-scaled)
//   [4MB,...)      gx   : per dir 128MB: [mt 4096][w4 4][g*2+cp 8][lane 64][16B]
#define WX_OFF   0u
#define BIAS_OFF (1u<<20)
#define GX_OFF   (4u<<20)
#define GXD ((size_t)4096 * 32768)   // 128MB per dir

// gate scale: y = s_g * (W z + b); f,i,o: s=-log2e -> sig = rcp(1+exp2(y))
//                                   c:     s=+2log2e -> tanh = 1-2*rcp(exp2(y)+1)
#define SC_SIG (-1.4426950408889634f)
#define SC_TANH (2.8853900817779268f)

__device__ __forceinline__ void load_lds16(const void* g, void* l) {
  __builtin_amdgcn_global_load_lds((const __attribute__((address_space(1))) void*)g,
                                   (__attribute__((address_space(3))) void*)l, 16, 0, 0);
}

// ---------------- kernel 1: Wx -> f16 (pre-scaled), bias table -----------------
struct PrepP { const float* W[8]; const float* Bv[8]; f16* wx; float* bias; };

__global__ __launch_bounds__(256) void k_prep(PrepP p) {
  const int u = blockIdx.x * 256 + threadIdx.x;       // 131072 threads exactly
  const int k4 = (u & 63) * 4;
  const int n = (u >> 6) & 1023;
  const int dir = u >> 16;
  const int g = n >> 8;
  const float s = (g == 2) ? SC_TANH : SC_SIG;
  const float* src = p.W[dir * 4 + g] + (size_t)(n & 255) * CS + HID + k4;
  f32x4 a = *(const f32x4*)src;
  f16x4 v;
  #pragma unroll
  for (int j = 0; j < 4; ++j) v[j] = (f16)(a[j] * s);
  *(f16x4*)(p.wx + ((size_t)dir * 1024 + n) * 256 + k4) = v;
  if (u < 2048) {
    const int gg = (u >> 8) & 3;
    const float ss = (gg == 2) ? SC_TANH : SC_SIG;
    p.bias[u] = p.Bv[(u >> 10) * 4 + gg][u & 255] * ss;
  }
}

// ---------------- kernel 2: Gx = X @ Wx^T + b  (f16, k_rec layout) --------------
struct GemP { const float* X; const f16* wx; const float* bias; f16* gx; int d0, nd; };

__global__ __launch_bounds__(256) void k_gemm(GemP p) {
  __shared__ float As[128 * 64];   // 32KB, rows 256B, XOR-swizzled
  __shared__ f16   Bs[128 * 64];   // 16KB, rows 128B, XOR-swizzled
  const int tid = threadIdx.x, l = tid & 63, w = tid >> 6;
  const int lp = l & 15, lg = l >> 4;
  const int NB = 8 * p.nd;
  const int nb = blockIdx.x % NB, mb = blockIdx.x / NB;
  const int m0 = mb * 128;
  const int wm = w >> 1, wn = w & 1;

  f32x4 acc[4][4];
  #pragma unroll
  for (int a = 0; a < 4; ++a)
    #pragma unroll
    for (int b = 0; b < 4; ++b) acc[a][b] = (f32x4){0.f, 0.f, 0.f, 0.f};

  auto stage = [&](int kb) {
    #pragma unroll
    for (int j = 0; j < 8; ++j) {
      const int i = w * 8 + j;
      const int rl = i * 4 + lg;
      const int kc = (lp * 16) ^ ((rl & 7) << 4);
      const char* g = (const char*)p.X + ((size_t)(m0 + rl) * 256 + (size_t)kb * 64) * 4 + kc;
      load_lds16(g, (char*)As + i * 1024 + l * 16);
    }
    #pragma unroll
    for (int j = 0; j < 4; ++j) {
      const int i = w * 4 + j;
      const int rl = i * 8 + (l >> 3);
      const int kc = ((l & 7) * 16) ^ ((rl & 7) << 4);
      const char* g = (const char*)p.wx + ((size_t)(p.d0 * 1024 + nb * 128 + rl) * 256 + (size_t)kb * 64) * 2 + kc;
      load_lds16(g, (char*)Bs + i * 1024 + l * 16);
    }
  };

  stage(0);
  for (int kb = 0; kb < 4; ++kb) {
    __syncthreads();
    #pragma unroll
    for (int ks = 0; ks < 2; ++ks) {
      f16x8 af[4];
      #pragma unroll
      for (int mi = 0; mi < 4; ++mi) {
        const int r = wm * 64 + mi * 16 + lp;
        const int kbyte = ks * 128 + lg * 32;
        const int sw = (r & 7) << 4;
        f32x4 a0 = *(const f32x4*)((const char*)As + r * 256 + (kbyte ^ sw));
        f32x4 a1 = *(const f32x4*)((const char*)As + r * 256 + ((kbyte + 16) ^ sw));
        f16x8 v;
        #pragma unroll
        for (int j = 0; j < 4; ++j) { v[j] = (f16)a0[j]; v[4 + j] = (f16)a1[j]; }
        af[mi] = v;
      }
      #pragma unroll
      for (int ni = 0; ni < 4; ++ni) {
        const int rn = wn * 64 + ni * 16 + lp;
        const int kbyte = (ks * 64 + lg * 16) ^ ((rn & 7) << 4);
        f16x8 bf = *(const f16x8*)((const char*)Bs + rn * 128 + kbyte);
        #pragma unroll
        for (int mi = 0; mi < 4; ++mi)
          acc[mi][ni] = __builtin_amdgcn_mfma_f32_16x16x32_f16(af[mi], bf, acc[mi][ni], 0, 0, 0);
      }
    }
    if (kb < 3) { __syncthreads(); stage(kb + 1); }
  }

  // epilogue: +bias, f16, store in k_rec layout
  #pragma unroll
  for (int ni = 0; ni < 4; ++ni) {
    const int n_all = nb * 128 + wn * 64 + ni * 16 + lp;
    const float bv = p.bias[p.d0 * 1024 + n_all];
    const int gdl = n_all >> 10;
    const int n = n_all & 1023;
    const int g = n >> 8, hid = n & 255;
    const int wr = hid >> 6, c = (hid >> 4) & 3;
    #pragma unroll
    for (int mi = 0; mi < 4; ++mi) {
      const int mt = (m0 + wm * 64 + mi * 16) >> 4;
      f16x4 h4;
      #pragma unroll
      for (int r = 0; r < 4; ++r) h4[r] = (f16)(acc[mi][ni][r] + bv);
      char* dst = (char*)p.gx + (size_t)gdl * GXD
                + ((((size_t)mt * 4 + wr) * 8) + g * 2 + (c >> 1)) * 1024
                + (size_t)l * 16 + (c & 1) * 8;
      *(f16x4*)dst = h4;
    }
  }
}

// ---------------- kernel 3: block-local recurrence, 8 waves, 2/SIMD ------------
// Wave w owns hid slice [w*32, w*32+32): 4 gates x 2 c-tiles.
// LDS: [0,147456)        wt: wave w at w*18432, 18 slots x 1KB:
//                        g<3: slot (g*2+c)*2+(ks-6) for ks 6,7  -> 0..11
//                        g=3: slot 12+c*3+(ks-5)    for ks 5..7 -> 12..17
//      [147456,163840)   h: 2 buffers x (16 rows x 256 hid f16), byte ^= (row&7)<<4
#define WTB_STRIDE 18432
#define HB_OFF  147456
#define REC_LDS 163840

struct RecP { const float* W[8]; const f16* gx; float* out; int d0; };

__global__ __launch_bounds__(512, 2) void k_rec(RecP p) {
  extern __shared__ char smem[];
  const int tid = threadIdx.x, l = tid & 63, w = tid >> 6;   // w 0..7
  const int lp = l & 15, lg = l >> 4;
  const int bx = blockIdx.x;
  const int dirl = bx >> 3;
  const int dir = p.d0 + dirl;
  const int bt = bx & 7;

  char* wtb = smem + w * WTB_STRIDE;
  const char* gxd = (const char*)p.gx + (size_t)dirl * GXD;

  // ---- weights (pre-scaled per gate): regs = ks0-5 (g<3) / ks0-4 (g3);
  //      LDS = ks6,7 all + ks5 of g3 ----
  f16x8 Br[4][2][6];   // [3][c][5] never written/read -> DCE'd (46 live frags)
  #pragma unroll
  for (int g = 0; g < 4; ++g) {
    const float s = (g == 2) ? SC_TANH : SC_SIG;
    #pragma unroll
    for (int c = 0; c < 2; ++c) {
      const float* wr = p.W[dir * 4 + g] + (size_t)(w * 32 + c * 16 + lp) * CS;
      #pragma unroll
      for (int ks = 0; ks < 8; ++ks) {
        f32x4 a0 = *(const f32x4*)(wr + ks * 32 + lg * 8);
        f32x4 a1 = *(const f32x4*)(wr + ks * 32 + lg * 8 + 4);
        f16x8 v;
        #pragma unroll
        for (int j = 0; j < 4; ++j) { v[j] = (f16)(a0[j] * s); v[4 + j] = (f16)(a1[j] * s); }
        if (g == 3 && ks == 5)
          *(f16x8*)(wtb + (12 + c * 3) * 1024 + (size_t)l * 16) = v;
        else if (ks >= 6) {
          const int slot = (g < 3) ? ((g * 2 + c) * 2 + (ks - 6)) : (12 + c * 3 + (ks - 5));
          *(f16x8*)(wtb + slot * 1024 + (size_t)l * 16) = v;
        } else
          Br[g][c][ks] = v;
      }
    }
  }

  float cst[2][4];
  #pragma unroll
  for (int c = 0; c < 2; ++c)
    #pragma unroll
    for (int r = 0; r < 4; ++r) cst[c][r] = 0.f;

  int tt = dir ? (SEQ - 1) : 0;
  const int stp = dir ? -1 : 1;

  float* outb = p.out + ((size_t)(bt * 16) * 512 + (size_t)dir * 256);
  const int vo = (lg * 4) * 512 + w * 32 + lp;     // dword offset at r=0,c=0

  // gx prefetch: one f16x8 per gate covers BOTH c-tiles of this wave
  f16x8 q[4];
  auto issue_q = [&](int mt) {
    const char* s = gxd + ((size_t)mt * 4 + (w >> 1)) * 8192 + (size_t)l * 16;
    #pragma unroll
    for (int g = 0; g < 4; ++g)
      q[g] = *(const f16x8*)(s + (g * 2 + (w & 1)) * 1024);
  };

  issue_q(tt * 8 + bt);
  asm volatile("s_waitcnt vmcnt(0) lgkmcnt(0)" ::: "memory");
  __builtin_amdgcn_sched_barrier(0);
  __builtin_amdgcn_s_barrier();

  for (int t = 0; t < SEQ; ++t, tt += stp) {
    const int pr = ((t & 1) ^ 1) * 8192;   // read h buffer (valid for t>0)
    const int pw = (t & 1) * 8192;         // write h buffer

    // q(t) landed: queue = [4 c0-stores][4 q-loads][4 c1-stores] -> vmcnt(4)
    asm volatile("s_waitcnt vmcnt(4)" ::: "memory");
    __builtin_amdgcn_sched_barrier(0);

    float* outt = outb + (size_t)tt * (128 * 512);
    int ttn = tt + stp;
    ttn = ttn < 0 ? 0 : (ttn > SEQ - 1 ? SEQ - 1 : ttn);

    #pragma unroll
    for (int c = 0; c < 2; ++c) {
      f32x4 acc[4];
      #pragma unroll
      for (int g = 0; g < 4; ++g)
        #pragma unroll
        for (int r = 0; r < 4; ++r) acc[g][r] = (float)q[g][c * 4 + r];

      if (c == 1) {
        // old q fully consumed -> prefetch next step's gx
        issue_q(ttn * 8 + bt);
        __builtin_amdgcn_sched_barrier(0);
      }
      if (t > 0) {
        #pragma unroll
        for (int ks = 0; ks < 8; ++ks) {
          const int byte = ((lp * 512 + ks * 64 + lg * 16) ^ ((lp & 7) << 4)) + pr;
          f16x8 av = *(const f16x8*)(smem + HB_OFF + byte);
          #pragma unroll
          for (int g = 0; g < 4; ++g) {
            f16x8 bv;
            if (ks < 5 || (ks == 5 && g < 3)) {
              bv = Br[g][c][ks];
            } else if (ks == 5) {
              bv = *(const f16x8*)(wtb + (12 + c * 3) * 1024 + (size_t)l * 16);
            } else {
              const int slot = (g < 3) ? ((g * 2 + c) * 2 + (ks - 6)) : (12 + c * 3 + (ks - 5));
              bv = *(const f16x8*)(wtb + slot * 1024 + (size_t)l * 16);
            }
            acc[g] = __builtin_amdgcn_mfma_f32_16x16x32_f16(av, bv, acc[g], 0, 0, 0);
          }
        }
      }
      #pragma unroll
      for (int r = 0; r < 4; ++r) {
        // pre-activations arrive exp2-scaled (f,i,o: -log2e ; c: +2log2e)
        const float fg = __builtin_amdgcn_rcpf(1.0f + __builtin_amdgcn_exp2f(acc[0][r]));
        const float ig = __builtin_amdgcn_rcpf(1.0f + __builtin_amdgcn_exp2f(acc[1][r]));
        const float cg = 1.0f - 2.0f * __builtin_amdgcn_rcpf(__builtin_amdgcn_exp2f(acc[2][r]) + 1.0f);
        const float og = __builtin_amdgcn_rcpf(1.0f + __builtin_amdgcn_exp2f(acc[3][r]));
        const float cn = fg * cst[c][r] + ig * cg;
        cst[c][r] = cn;
        const float th = 1.0f - 2.0f * __builtin_amdgcn_rcpf(__builtin_amdgcn_exp2f(cn * SC_TANH) + 1.0f);
        const float h = og * th;
        const int row = lg * 4 + r;
        const int hid = w * 32 + c * 16 + lp;
        const int hbyte = ((row * 512 + hid * 2) ^ ((row & 7) << 4)) + pw;
        *(f16*)(smem + HB_OFF + hbyte) = (f16)h;
        outt[vo + r * 512 + c * 16] = h;
      }
    }

    // h writes visible to all waves before next step's h reads
    asm volatile("s_waitcnt lgkmcnt(0)" ::: "memory");
    __builtin_amdgcn_sched_barrier(0);
    __builtin_amdgcn_s_barrier();
  }
}

// ---------------- launch -------------------------------------------------------
extern "C" void kernel_launch(void* const* d_in, const int* in_sizes, int n_in,
                              void* d_out, int out_size, void* d_ws, size_t ws_size,
                              hipStream_t stream) {
  (void)in_sizes; (void)n_in; (void)out_size;
  PrepP pp;
  const float* X = (const float*)d_in[0];
  for (int i = 0; i < 8; ++i) {
    pp.W[i]  = (const float*)d_in[1 + 2 * i];
    pp.Bv[i] = (const float*)d_in[2 + 2 * i];
  }
  char* ws = (char*)d_ws;
  pp.wx = (f16*)(ws + WX_OFF);
  pp.bias = (float*)(ws + BIAS_OFF);
  f16* gx = (f16*)(ws + GX_OFF);

  int nd;
  if (ws_size >= (size_t)GX_OFF + 2 * GXD) nd = 2;
  else if (ws_size >= (size_t)GX_OFF + GXD) nd = 1;
  else return;

  hipFuncSetAttribute(reinterpret_cast<const void*>(k_rec),
                      hipFuncAttributeMaxDynamicSharedMemorySize, REC_LDS);

  k_prep<<<dim3(512), dim3(256), 0, stream>>>(pp);

  const int passes = (nd == 2) ? 1 : 2;
  for (int ps = 0; ps < passes; ++ps) {
    const int d0 = (nd == 2) ? 0 : ps;
    GemP gp; gp.X = X; gp.wx = pp.wx; gp.bias = pp.bias; gp.gx = gx; gp.d0 = d0; gp.nd = nd;
    k_gemm<<<dim3(512 * 8 * nd), dim3(256), 0, stream>>>(gp);
    RecP rp;
    for (int i = 0; i < 8; ++i) rp.W[i] = pp.W[i];
    rp.gx = gx; rp.out = (float*)d_out; rp.d0 = d0;
    k_rec<<<dim3(8 * nd), dim3(512), REC_LDS, stream>>>(rp);
  }
}

// Round 9
// 1461.228 us; speedup vs baseline: 1.7415x; 1.0515x over previous
//
#include <hip/hip_runtime.h>
#include <stdint.h>

#define SEQ 512
#define BATCH 128
#define INDIM 256
#define HID 256
#define CS 512

typedef _Float16 f16;
typedef __attribute__((ext_vector_type(8))) _Float16 f16x8;
typedef __attribute__((ext_vector_type(4))) _Float16 f16x4;
typedef __attribute__((ext_vector_type(4))) float f32x4;
typedef __attribute__((ext_vector_type(2))) uint32_t u32x2;

// ws layout:
//   [0,1MB)        wx   : [2][1024 n][256 k] f16   (pre-scaled by gate exp2-factor)
//   [1MB,1MB+8KB)  bias : [2048] f32               (pre-scaled)
//   [2MB,2.5MB)    ex   : [dir 2][bt 8][half 2][slot 2][2048] u32 tagged-h
//   [4MB,...)      gx   : per dir 128MB: [mt 4096][half 2][w 8][g 4][lane 64][8B]
#define WX_OFF   0u
#define BIAS_OFF (1u<<20)
#define EX_OFF   (2u<<20)
#define EX_BYTES (2*8*2*2*2048*4)
#define GX_OFF   (4u<<20)
#define GXD ((size_t)4096 * 32768)   // 128MB per dir

// gate scale: y = s_g*(Wz+b); f,i,o: s=-log2e -> sig = rcp(1+exp2(y))
//                              c:    s=+2log2e -> tanh = 1-2*rcp(exp2(y)+1)
#define SC_SIG (-1.4426950408889634f)
#define SC_TANH (2.8853900817779268f)

__device__ __forceinline__ void load_lds16(const void* g, void* l) {
  __builtin_amdgcn_global_load_lds((const __attribute__((address_space(1))) void*)g,
                                   (__attribute__((address_space(3))) void*)l, 16, 0, 0);
}

// ---------------- kernel 1: Wx -> f16 (pre-scaled), bias table -----------------
struct PrepP { const float* W[8]; const float* Bv[8]; f16* wx; float* bias; };

__global__ __launch_bounds__(256) void k_prep(PrepP p) {
  const int u = blockIdx.x * 256 + threadIdx.x;       // 131072 threads exactly
  const int k4 = (u & 63) * 4;
  const int n = (u >> 6) & 1023;
  const int dir = u >> 16;
  const int g = n >> 8;
  const float s = (g == 2) ? SC_TANH : SC_SIG;
  const float* src = p.W[dir * 4 + g] + (size_t)(n & 255) * CS + HID + k4;
  f32x4 a = *(const f32x4*)src;
  f16x4 v;
  #pragma unroll
  for (int j = 0; j < 4; ++j) v[j] = (f16)(a[j] * s);
  *(f16x4*)(p.wx + ((size_t)dir * 1024 + n) * 256 + k4) = v;
  if (u < 2048) {
    const int gg = (u >> 8) & 3;
    const float ss = (gg == 2) ? SC_TANH : SC_SIG;
    p.bias[u] = p.Bv[(u >> 10) * 4 + gg][u & 255] * ss;
  }
}

// ---------------- kernel 2: Gx = X @ Wx^T + b  (f16, split-H layout) ------------
struct GemP { const float* X; const f16* wx; const float* bias; f16* gx; int d0, nd; };

__global__ __launch_bounds__(256) void k_gemm(GemP p) {
  __shared__ float As[128 * 64];   // 32KB, rows 256B, XOR-swizzled
  __shared__ f16   Bs[128 * 64];   // 16KB, rows 128B, XOR-swizzled
  const int tid = threadIdx.x, l = tid & 63, w = tid >> 6;
  const int lp = l & 15, lg = l >> 4;
  const int NB = 8 * p.nd;
  const int nb = blockIdx.x % NB, mb = blockIdx.x / NB;
  const int m0 = mb * 128;
  const int wm = w >> 1, wn = w & 1;

  f32x4 acc[4][4];
  #pragma unroll
  for (int a = 0; a < 4; ++a)
    #pragma unroll
    for (int b = 0; b < 4; ++b) acc[a][b] = (f32x4){0.f, 0.f, 0.f, 0.f};

  auto stage = [&](int kb) {
    #pragma unroll
    for (int j = 0; j < 8; ++j) {
      const int i = w * 8 + j;
      const int rl = i * 4 + lg;
      const int kc = (lp * 16) ^ ((rl & 7) << 4);
      const char* g = (const char*)p.X + ((size_t)(m0 + rl) * 256 + (size_t)kb * 64) * 4 + kc;
      load_lds16(g, (char*)As + i * 1024 + l * 16);
    }
    #pragma unroll
    for (int j = 0; j < 4; ++j) {
      const int i = w * 4 + j;
      const int rl = i * 8 + (l >> 3);
      const int kc = ((l & 7) * 16) ^ ((rl & 7) << 4);
      const char* g = (const char*)p.wx + ((size_t)(p.d0 * 1024 + nb * 128 + rl) * 256 + (size_t)kb * 64) * 2 + kc;
      load_lds16(g, (char*)Bs + i * 1024 + l * 16);
    }
  };

  stage(0);
  for (int kb = 0; kb < 4; ++kb) {
    __syncthreads();
    #pragma unroll
    for (int ks = 0; ks < 2; ++ks) {
      f16x8 af[4];
      #pragma unroll
      for (int mi = 0; mi < 4; ++mi) {
        const int r = wm * 64 + mi * 16 + lp;
        const int kbyte = ks * 128 + lg * 32;
        const int sw = (r & 7) << 4;
        f32x4 a0 = *(const f32x4*)((const char*)As + r * 256 + (kbyte ^ sw));
        f32x4 a1 = *(const f32x4*)((const char*)As + r * 256 + ((kbyte + 16) ^ sw));
        f16x8 v;
        #pragma unroll
        for (int j = 0; j < 4; ++j) { v[j] = (f16)a0[j]; v[4 + j] = (f16)a1[j]; }
        af[mi] = v;
      }
      #pragma unroll
      for (int ni = 0; ni < 4; ++ni) {
        const int rn = wn * 64 + ni * 16 + lp;
        const int kbyte = (ks * 64 + lg * 16) ^ ((rn & 7) << 4);
        f16x8 bf = *(const f16x8*)((const char*)Bs + rn * 128 + kbyte);
        #pragma unroll
        for (int mi = 0; mi < 4; ++mi)
          acc[mi][ni] = __builtin_amdgcn_mfma_f32_16x16x32_f16(af[mi], bf, acc[mi][ni], 0, 0, 0);
      }
    }
    if (kb < 3) { __syncthreads(); stage(kb + 1); }
  }

  // epilogue: +bias, f16, store in split-H k_rec layout (consumer lane == l)
  #pragma unroll
  for (int ni = 0; ni < 4; ++ni) {
    const int n_all = nb * 128 + wn * 64 + ni * 16 + lp;
    const float bv = p.bias[p.d0 * 1024 + n_all];
    const int gdl = n_all >> 10;
    const int n = n_all & 1023;
    const int g = n >> 8, hid = n & 255;
    const int half = hid >> 7, w8 = (hid >> 4) & 7;
    #pragma unroll
    for (int mi = 0; mi < 4; ++mi) {
      const int mt = (m0 + wm * 64 + mi * 16) >> 4;
      f16x4 h4;
      #pragma unroll
      for (int r = 0; r < 4; ++r) h4[r] = (f16)(acc[mi][ni][r] + bv);
      char* dst = (char*)p.gx + (size_t)gdl * GXD
                + ((((size_t)mt * 2 + half) * 8 + w8) * 4 + g) * 512 + (size_t)l * 8;
      *(f16x4*)dst = h4;
    }
  }
}

// ---------------- kernel 3: split-H recurrence, 2 blocks per group -------------
// LDS: [0,16384)       h: 2 buffers x (16 rows x 256 hid f16), byte ^= (row&7)<<4
//      [16384,81920)   wt: wave w at 16384+w*8192, 8 frags (g x kk{2,3} partner)
#define HB_OFF 0
#define WT_OFF 16384
#define REC_LDS 81920

struct RecP { const float* W[8]; const f16* gx; uint32_t* ex; float* out; int d0; };

__global__ __launch_bounds__(512, 2) void k_rec(RecP p) {
  extern __shared__ char smem[];
  const int tid = threadIdx.x, l = tid & 63, w = tid >> 6;   // w 0..7
  const int lp = l & 15, lg = l >> 4;
  const int bx = blockIdx.x;
  const int bt = bx & 7;
  const int half = (bx >> 3) & 1;          // partner block = bx ^ 8 (same XCD)
  const int dirl = bx >> 4;
  const int dir = p.d0 + dirl;

  char* wtb = smem + WT_OFF + w * 8192;
  const char* gxd = (const char*)p.gx + (size_t)dirl * GXD;

  // ---- weights: own-k-first index: Br[g][i], i<4: k=half*128+i*32 (own h half),
  //      i>=4: k=(1-half)*128+(i-4)*32 (partner). i=6,7 live in LDS. ----
  f16x8 Br[4][6];
  #pragma unroll
  for (int g = 0; g < 4; ++g) {
    const float s = (g == 2) ? SC_TANH : SC_SIG;
    const float* wrow = p.W[dir * 4 + g] + (size_t)(half * 128 + w * 16 + lp) * CS;
    #pragma unroll
    for (int i = 0; i < 8; ++i) {
      const int kb = (i < 4 ? half * 128 + i * 32 : (1 - half) * 128 + (i - 4) * 32) + lg * 8;
      f32x4 a0 = *(const f32x4*)(wrow + kb);
      f32x4 a1 = *(const f32x4*)(wrow + kb + 4);
      f16x8 v;
      #pragma unroll
      for (int j = 0; j < 4; ++j) { v[j] = (f16)(a0[j] * s); v[4 + j] = (f16)(a1[j] * s); }
      if (i >= 6) *(f16x8*)(wtb + (g * 2 + (i - 6)) * 1024 + (size_t)l * 16) = v;
      else Br[g][i] = v;
    }
  }

  float cst[4];
  #pragma unroll
  for (int r = 0; r < 4; ++r) cst[r] = 0.f;

  int tt = dir ? (SEQ - 1) : 0;
  const int stp = dir ? -1 : 1;

  // ex: [dir][bt][half][slot][2048 u32]
  uint32_t* exg = p.ex + (size_t)(dir * 8 + bt) * (2 * 2 * 2048);
  uint32_t* ex_own = exg + half * 2 * 2048;
  const uint32_t* ex_par = exg + (1 - half) * 2 * 2048;
  const int pubw = (lg * 4) * 128 + w * 16 + lp;          // + r*128
  // partner staging: thread stages words u=tid*4..+3 -> LDS row u>>7, col (u&127)
  const int stg_row = tid >> 5;
  const int stg_byte = (stg_row * 512 + ((1 - half) * 128 + ((tid * 4) & 127)) * 2)
                       ^ ((stg_row & 7) << 4);

  float* outb = p.out + ((size_t)(bt * 16) * 512 + (size_t)dir * 256 + half * 128 + w * 16);
  const int vo = (lg * 4) * 512 + lp;                      // + r*512

  // gx prefetch: f16x4 per gate (this wave's 16-hid slice, 4 batch rows)
  f16x4 q[4];
  auto issue_q = [&](int mt) {
    const char* s = gxd + (((size_t)mt * 2 + half) * 8 + w) * 2048 + (size_t)l * 8;
    #pragma unroll
    for (int g = 0; g < 4; ++g)
      q[g] = *(const f16x4*)(s + g * 512);
  };

  uint32_t sv[4];      // speculative tagged partner words

  issue_q(tt * 8 + bt);
  asm volatile("s_waitcnt vmcnt(0) lgkmcnt(0)" ::: "memory");
  __builtin_amdgcn_sched_barrier(0);
  __builtin_amdgcn_s_barrier();

  for (int t = 0; t < SEQ; ++t, tt += stp) {
    const int pr = ((t & 1) ^ 1) * 8192;   // h(t-1) buffer
    const int pw = (t & 1) * 8192;         // h(t) buffer

    // own-half a-frags (k reindexed: own = half*128 + kk*32)
    f16x8 a_own[4];
    #pragma unroll
    for (int kk = 0; kk < 4; ++kk) {
      const int byte = ((lp * 512 + half * 256 + kk * 64 + lg * 16) ^ ((lp & 7) << 4)) + pr;
      a_own[kk] = *(const f16x8*)(smem + HB_OFF + byte);
    }
    // q(t) landed: exactly 12 vm ops (4 pub + 4 out + 4 spec) issued after it
    asm volatile("s_waitcnt vmcnt(12)" ::: "memory");
    __builtin_amdgcn_sched_barrier(0);

    f32x4 acc[4];
    #pragma unroll
    for (int g = 0; g < 4; ++g)
      #pragma unroll
      for (int r = 0; r < 4; ++r) acc[g][r] = (float)q[g][r];

    if (t > 0) {
      // spin: need partner tag == t in slot (t-1)&1 (sv speculatively loaded)
      const uint32_t want = (uint32_t)t << 16;
      uint32_t mx = 0;
      #pragma unroll
      for (int j = 0; j < 4; ++j) { uint32_t x = sv[j] ^ want; mx = x > mx ? x : mx; }
      const uint32_t* ebs = ex_par + ((t - 1) & 1) * 2048 + tid * 4;
      while (__ballot(mx < 0x10000u) != 0xFFFFFFFFFFFFFFFFull) {
        __builtin_amdgcn_s_sleep(1);
        #pragma unroll
        for (int j = 0; j < 4; ++j)
          sv[j] = __hip_atomic_load(ebs + j, __ATOMIC_RELAXED, __HIP_MEMORY_SCOPE_AGENT);
        mx = 0;
        #pragma unroll
        for (int j = 0; j < 4; ++j) { uint32_t x = sv[j] ^ want; mx = x > mx ? x : mx; }
      }
      // stage partner h(t-1) -> LDS[pr] partner half (4 f16 -> one b64)
      u32x2 pk;
      pk[0] = (sv[0] & 0xffffu) | (sv[1] << 16);
      pk[1] = (sv[2] & 0xffffu) | (sv[3] << 16);
      *(u32x2*)(smem + HB_OFF + pr + stg_byte) = pk;
    }

    // next-step gx prefetch (pinned here: post-spin, pre-publish)
    __builtin_amdgcn_sched_barrier(0);
    {
      int ttn = tt + stp;
      ttn = ttn < 0 ? 0 : (ttn > SEQ - 1 ? SEQ - 1 : ttn);
      issue_q(ttn * 8 + bt);
    }
    __builtin_amdgcn_sched_barrier(0);

    if (t > 0) {
      #pragma unroll
      for (int kk = 0; kk < 4; ++kk)
        #pragma unroll
        for (int g = 0; g < 4; ++g)
          acc[g] = __builtin_amdgcn_mfma_f32_16x16x32_f16(a_own[kk], Br[g][kk], acc[g], 0, 0, 0);
    }

    asm volatile("s_waitcnt lgkmcnt(0)" ::: "memory");   // stage visible
    __builtin_amdgcn_sched_barrier(0);
    __builtin_amdgcn_s_barrier();

    if (t > 0) {
      f16x8 a_par[4];
      #pragma unroll
      for (int kk = 0; kk < 4; ++kk) {
        const int byte = ((lp * 512 + (1 - half) * 256 + kk * 64 + lg * 16) ^ ((lp & 7) << 4)) + pr;
        a_par[kk] = *(const f16x8*)(smem + HB_OFF + byte);
      }
      #pragma unroll
      for (int kk = 0; kk < 2; ++kk)
        #pragma unroll
        for (int g = 0; g < 4; ++g)
          acc[g] = __builtin_amdgcn_mfma_f32_16x16x32_f16(a_par[kk], Br[g][4 + kk], acc[g], 0, 0, 0);
      #pragma unroll
      for (int kk = 2; kk < 4; ++kk)
        #pragma unroll
        for (int g = 0; g < 4; ++g) {
          f16x8 bv = *(const f16x8*)(wtb + (g * 2 + (kk - 2)) * 1024 + (size_t)l * 16);
          acc[g] = __builtin_amdgcn_mfma_f32_16x16x32_f16(a_par[kk], bv, acc[g], 0, 0, 0);
        }
    }

    float* outt = outb + (size_t)tt * (128 * 512);
    const int hid_lane = half * 128 + w * 16 + lp;
    #pragma unroll
    for (int r = 0; r < 4; ++r) {
      const float fg = __builtin_amdgcn_rcpf(1.0f + __builtin_amdgcn_exp2f(acc[0][r]));
      const float ig = __builtin_amdgcn_rcpf(1.0f + __builtin_amdgcn_exp2f(acc[1][r]));
      const float cg = 1.0f - 2.0f * __builtin_amdgcn_rcpf(__builtin_amdgcn_exp2f(acc[2][r]) + 1.0f);
      const float og = __builtin_amdgcn_rcpf(1.0f + __builtin_amdgcn_exp2f(acc[3][r]));
      const float cn = fg * cst[r] + ig * cg;
      cst[r] = cn;
      const float th = 1.0f - 2.0f * __builtin_amdgcn_rcpf(__builtin_amdgcn_exp2f(cn * SC_TANH) + 1.0f);
      const float h = og * th;
      const int row = lg * 4 + r;
      const int hbyte = ((row * 512 + hid_lane * 2) ^ ((row & 7) << 4)) + pw;
      *(f16*)(smem + HB_OFF + hbyte) = (f16)h;          // own half -> LDS[pw]
      union { f16 f; uint16_t u; } hb; hb.f = (f16)h;
      __hip_atomic_store(ex_own + (t & 1) * 2048 + pubw + r * 128,
                         ((uint32_t)(t + 1) << 16) | (uint32_t)hb.u,
                         __ATOMIC_RELAXED, __HIP_MEMORY_SCOPE_AGENT);
      outt[vo + r * 512] = h;
    }

    // speculative partner loads for step t+1 (tag t+1, slot t&1)
    {
      const uint32_t* eb = ex_par + (t & 1) * 2048 + tid * 4;
      #pragma unroll
      for (int j = 0; j < 4; ++j)
        sv[j] = __hip_atomic_load(eb + j, __ATOMIC_RELAXED, __HIP_MEMORY_SCOPE_AGENT);
    }

    asm volatile("s_waitcnt lgkmcnt(0)" ::: "memory");   // h(t) LDS writes done
    __builtin_amdgcn_sched_barrier(0);
    __builtin_amdgcn_s_barrier();
  }
}

// ---------------- launch -------------------------------------------------------
extern "C" void kernel_launch(void* const* d_in, const int* in_sizes, int n_in,
                              void* d_out, int out_size, void* d_ws, size_t ws_size,
                              hipStream_t stream) {
  (void)in_sizes; (void)n_in; (void)out_size;
  PrepP pp;
  const float* X = (const float*)d_in[0];
  for (int i = 0; i < 8; ++i) {
    pp.W[i]  = (const float*)d_in[1 + 2 * i];
    pp.Bv[i] = (const float*)d_in[2 + 2 * i];
  }
  char* ws = (char*)d_ws;
  pp.wx = (f16*)(ws + WX_OFF);
  pp.bias = (float*)(ws + BIAS_OFF);
  uint32_t* ex = (uint32_t*)(ws + EX_OFF);
  f16* gx = (f16*)(ws + GX_OFF);

  int nd;
  if (ws_size >= (size_t)GX_OFF + 2 * GXD) nd = 2;
  else if (ws_size >= (size_t)GX_OFF + GXD) nd = 1;
  else return;

  hipFuncSetAttribute(reinterpret_cast<const void*>(k_rec),
                      hipFuncAttributeMaxDynamicSharedMemorySize, REC_LDS);

  hipMemsetAsync(ws + EX_OFF, 0, EX_BYTES, stream);
  k_prep<<<dim3(512), dim3(256), 0, stream>>>(pp);

  const int passes = (nd == 2) ? 1 : 2;
  for (int ps = 0; ps < passes; ++ps) {
    const int d0 = (nd == 2) ? 0 : ps;
    GemP gp; gp.X = X; gp.wx = pp.wx; gp.bias = pp.bias; gp.gx = gx; gp.d0 = d0; gp.nd = nd;
    k_gemm<<<dim3(512 * 8 * nd), dim3(256), 0, stream>>>(gp);
    RecP rp;
    for (int i = 0; i < 8; ++i) rp.W[i] = pp.W[i];
    rp.gx = gx; rp.ex = ex; rp.out = (float*)d_out; rp.d0 = d0;
    k_rec<<<dim3(16 * nd), dim3(512), REC_LDS, stream>>>(rp);
  }
}

// Round 10
// 1041.812 us; speedup vs baseline: 2.4426x; 1.4026x over previous
//
#include <hip/hip_runtime.h>
#include <stdint.h>

#define SEQ 512
#define BATCH 128
#define INDIM 256
#define HID 256
#define CS 512

typedef _Float16 f16;
typedef __attribute__((ext_vector_type(8))) _Float16 f16x8;
typedef __attribute__((ext_vector_type(4))) _Float16 f16x4;
typedef __attribute__((ext_vector_type(4))) float f32x4;
typedef __attribute__((ext_vector_type(2))) uint32_t u32x2;

// ws layout:
//   [0,1MB)        wx   : [2][1024 n][256 k] f16   (pre-scaled by gate exp2-factor)
//   [1MB,1MB+8KB)  bias : [2048] f32               (pre-scaled)
//   [2MB,2.5MB)    ex   : [dir 2][bt 8][half 2][slot 2][2048] u32 tagged-h
//   [4MB,...)      gx   : per dir 128MB: [mt 4096][half 2][w 8][g 4][lane 64][8B]
#define WX_OFF   0u
#define BIAS_OFF (1u<<20)
#define EX_OFF   (2u<<20)
#define EX_BYTES (2*8*2*2*2048*4)
#define GX_OFF   (4u<<20)
#define GXD ((size_t)4096 * 32768)   // 128MB per dir

// gate scale: y = s_g*(Wz+b); f,i,o: s=-log2e -> sig = rcp(1+exp2(y))
//                              c:    s=+2log2e -> tanh = 1-2*rcp(exp2(y)+1)
#define SC_SIG (-1.4426950408889634f)
#define SC_TANH (2.8853900817779268f)

__device__ __forceinline__ void load_lds16(const void* g, void* l) {
  __builtin_amdgcn_global_load_lds((const __attribute__((address_space(1))) void*)g,
                                   (__attribute__((address_space(3))) void*)l, 16, 0, 0);
}

// ---------------- kernel 1: Wx -> f16 (pre-scaled), bias table -----------------
struct PrepP { const float* W[8]; const float* Bv[8]; f16* wx; float* bias; };

__global__ __launch_bounds__(256) void k_prep(PrepP p) {
  const int u = blockIdx.x * 256 + threadIdx.x;       // 131072 threads exactly
  const int k4 = (u & 63) * 4;
  const int n = (u >> 6) & 1023;
  const int dir = u >> 16;
  const int g = n >> 8;
  const float s = (g == 2) ? SC_TANH : SC_SIG;
  const float* src = p.W[dir * 4 + g] + (size_t)(n & 255) * CS + HID + k4;
  f32x4 a = *(const f32x4*)src;
  f16x4 v;
  #pragma unroll
  for (int j = 0; j < 4; ++j) v[j] = (f16)(a[j] * s);
  *(f16x4*)(p.wx + ((size_t)dir * 1024 + n) * 256 + k4) = v;
  if (u < 2048) {
    const int gg = (u >> 8) & 3;
    const float ss = (gg == 2) ? SC_TANH : SC_SIG;
    p.bias[u] = p.Bv[(u >> 10) * 4 + gg][u & 255] * ss;
  }
}

// ---------------- kernel 2: Gx = X @ Wx^T + b  (f16, split-H layout) ------------
struct GemP { const float* X; const f16* wx; const float* bias; f16* gx; int d0, nd; };

__global__ __launch_bounds__(256) void k_gemm(GemP p) {
  __shared__ float As[128 * 64];   // 32KB, rows 256B, XOR-swizzled
  __shared__ f16   Bs[128 * 64];   // 16KB, rows 128B, XOR-swizzled
  const int tid = threadIdx.x, l = tid & 63, w = tid >> 6;
  const int lp = l & 15, lg = l >> 4;
  const int NB = 8 * p.nd;
  const int nb = blockIdx.x % NB, mb = blockIdx.x / NB;
  const int m0 = mb * 128;
  const int wm = w >> 1, wn = w & 1;

  f32x4 acc[4][4];
  #pragma unroll
  for (int a = 0; a < 4; ++a)
    #pragma unroll
    for (int b = 0; b < 4; ++b) acc[a][b] = (f32x4){0.f, 0.f, 0.f, 0.f};

  auto stage = [&](int kb) {
    #pragma unroll
    for (int j = 0; j < 8; ++j) {
      const int i = w * 8 + j;
      const int rl = i * 4 + lg;
      const int kc = (lp * 16) ^ ((rl & 7) << 4);
      const char* g = (const char*)p.X + ((size_t)(m0 + rl) * 256 + (size_t)kb * 64) * 4 + kc;
      load_lds16(g, (char*)As + i * 1024 + l * 16);
    }
    #pragma unroll
    for (int j = 0; j < 4; ++j) {
      const int i = w * 4 + j;
      const int rl = i * 8 + (l >> 3);
      const int kc = ((l & 7) * 16) ^ ((rl & 7) << 4);
      const char* g = (const char*)p.wx + ((size_t)(p.d0 * 1024 + nb * 128 + rl) * 256 + (size_t)kb * 64) * 2 + kc;
      load_lds16(g, (char*)Bs + i * 1024 + l * 16);
    }
  };

  stage(0);
  for (int kb = 0; kb < 4; ++kb) {
    __syncthreads();
    #pragma unroll
    for (int ks = 0; ks < 2; ++ks) {
      f16x8 af[4];
      #pragma unroll
      for (int mi = 0; mi < 4; ++mi) {
        const int r = wm * 64 + mi * 16 + lp;
        const int kbyte = ks * 128 + lg * 32;
        const int sw = (r & 7) << 4;
        f32x4 a0 = *(const f32x4*)((const char*)As + r * 256 + (kbyte ^ sw));
        f32x4 a1 = *(const f32x4*)((const char*)As + r * 256 + ((kbyte + 16) ^ sw));
        f16x8 v;
        #pragma unroll
        for (int j = 0; j < 4; ++j) { v[j] = (f16)a0[j]; v[4 + j] = (f16)a1[j]; }
        af[mi] = v;
      }
      #pragma unroll
      for (int ni = 0; ni < 4; ++ni) {
        const int rn = wn * 64 + ni * 16 + lp;
        const int kbyte = (ks * 64 + lg * 16) ^ ((rn & 7) << 4);
        f16x8 bf = *(const f16x8*)((const char*)Bs + rn * 128 + kbyte);
        #pragma unroll
        for (int mi = 0; mi < 4; ++mi)
          acc[mi][ni] = __builtin_amdgcn_mfma_f32_16x16x32_f16(af[mi], bf, acc[mi][ni], 0, 0, 0);
      }
    }
    if (kb < 3) { __syncthreads(); stage(kb + 1); }
  }

  // epilogue: +bias, f16, store in split-H k_rec layout (consumer lane == l)
  #pragma unroll
  for (int ni = 0; ni < 4; ++ni) {
    const int n_all = nb * 128 + wn * 64 + ni * 16 + lp;
    const float bv = p.bias[p.d0 * 1024 + n_all];
    const int gdl = n_all >> 10;
    const int n = n_all & 1023;
    const int g = n >> 8, hid = n & 255;
    const int half = hid >> 7, w8 = (hid >> 4) & 7;
    #pragma unroll
    for (int mi = 0; mi < 4; ++mi) {
      const int mt = (m0 + wm * 64 + mi * 16) >> 4;
      f16x4 h4;
      #pragma unroll
      for (int r = 0; r < 4; ++r) h4[r] = (f16)(acc[mi][ni][r] + bv);
      char* dst = (char*)p.gx + (size_t)gdl * GXD
                + ((((size_t)mt * 2 + half) * 8 + w8) * 4 + g) * 512 + (size_t)l * 8;
      *(f16x4*)dst = h4;
    }
  }
}

// ---------------- kernel 3: split-H recurrence, 2 blocks per group -------------
// LDS: [0,16384)       h: 2 buffers x (16 rows x 256 hid f16), byte ^= (row&7)<<4
//      [16384,81920)   wt: wave w at 16384+w*8192, 8 frags (g x kk{2,3} partner)
#define HB_OFF 0
#define WT_OFF 16384
#define REC_LDS 81920

struct RecP { const float* W[8]; const f16* gx; uint32_t* ex; float* out; int d0; };

__global__ __launch_bounds__(512, 2) void k_rec(RecP p) {
  extern __shared__ char smem[];
  const int tid = threadIdx.x, l = tid & 63, w = tid >> 6;   // w 0..7
  const int lp = l & 15, lg = l >> 4;
  const int bx = blockIdx.x;
  const int bt = bx & 7;
  const int half = (bx >> 3) & 1;          // partner block = bx ^ 8 (same XCD)
  const int dirl = bx >> 4;
  const int dir = p.d0 + dirl;

  char* wtb = smem + WT_OFF + w * 8192;
  const char* gxd = (const char*)p.gx + (size_t)dirl * GXD;

  // ---- weights: own-k-first index: Br[g][i], i<4: k=half*128+i*32 (own h half),
  //      i>=4: k=(1-half)*128+(i-4)*32 (partner). i=6,7 live in LDS. ----
  f16x8 Br[4][6];
  #pragma unroll
  for (int g = 0; g < 4; ++g) {
    const float s = (g == 2) ? SC_TANH : SC_SIG;
    const float* wrow = p.W[dir * 4 + g] + (size_t)(half * 128 + w * 16 + lp) * CS;
    #pragma unroll
    for (int i = 0; i < 8; ++i) {
      const int kb = (i < 4 ? half * 128 + i * 32 : (1 - half) * 128 + (i - 4) * 32) + lg * 8;
      f32x4 a0 = *(const f32x4*)(wrow + kb);
      f32x4 a1 = *(const f32x4*)(wrow + kb + 4);
      f16x8 v;
      #pragma unroll
      for (int j = 0; j < 4; ++j) { v[j] = (f16)(a0[j] * s); v[4 + j] = (f16)(a1[j] * s); }
      if (i >= 6) *(f16x8*)(wtb + (g * 2 + (i - 6)) * 1024 + (size_t)l * 16) = v;
      else Br[g][i] = v;
    }
  }

  float cst[4];
  #pragma unroll
  for (int r = 0; r < 4; ++r) cst[r] = 0.f;

  int tt = dir ? (SEQ - 1) : 0;
  const int stp = dir ? -1 : 1;

  // ex: [dir][bt][half][slot][2048 u32]
  uint32_t* exg = p.ex + (size_t)(dir * 8 + bt) * (2 * 2 * 2048);
  uint32_t* ex_own = exg + half * 2 * 2048;
  const uint32_t* ex_par = exg + (1 - half) * 2 * 2048;
  const int pubw = (lg * 4) * 128 + w * 16 + lp;          // + r*128
  // partner staging: thread stages words u=tid*4..+3 -> LDS row u>>7, col (u&127)
  const int stg_row = tid >> 5;
  const int stg_byte = (stg_row * 512 + ((1 - half) * 128 + ((tid * 4) & 127)) * 2)
                       ^ ((stg_row & 7) << 4);

  float* outb = p.out + ((size_t)(bt * 16) * 512 + (size_t)dir * 256 + half * 128 + w * 16);
  const int vo = (lg * 4) * 512 + lp;                      // + r*512

  // gx prefetch: f16x4 per gate (this wave's 16-hid slice, 4 batch rows)
  f16x4 q[4];
  auto issue_q = [&](int mt) {
    const char* s = gxd + (((size_t)mt * 2 + half) * 8 + w) * 2048 + (size_t)l * 8;
    #pragma unroll
    for (int g = 0; g < 4; ++g)
      q[g] = *(const f16x4*)(s + g * 512);
  };

  issue_q(tt * 8 + bt);
  asm volatile("s_waitcnt vmcnt(0) lgkmcnt(0)" ::: "memory");
  __builtin_amdgcn_sched_barrier(0);
  __builtin_amdgcn_s_barrier();

  for (int t = 0; t < SEQ; ++t, tt += stp) {
    const int pr = ((t & 1) ^ 1) * 8192;   // h(t-1) buffer
    const int pw = (t & 1) * 8192;         // h(t) buffer

    // spec loads for partner tag t (slot (t-1)&1): issued FIRST, checked after
    // own-MFMA (~400cy later) so LLC visibility latency is hidden.
    uint64_t sv0, sv1;
    const uint64_t* eb = (const uint64_t*)(ex_par + ((t - 1) & 1) * 2048) + tid * 2;
    sv0 = __hip_atomic_load(eb + 0, __ATOMIC_RELAXED, __HIP_MEMORY_SCOPE_AGENT);
    sv1 = __hip_atomic_load(eb + 1, __ATOMIC_RELAXED, __HIP_MEMORY_SCOPE_AGENT);
    __builtin_amdgcn_sched_barrier(0);

    // own-half a-frags (k reindexed: own = half*128 + kk*32)
    f16x8 a_own[4];
    #pragma unroll
    for (int kk = 0; kk < 4; ++kk) {
      const int byte = ((lp * 512 + half * 256 + kk * 64 + lg * 16) ^ ((lp & 7) << 4)) + pr;
      a_own[kk] = *(const f16x8*)(smem + HB_OFF + byte);
    }
    // q(t) retired: ops newer than q(t) = [4 pub][4 out][2 spec] = 10
    asm volatile("s_waitcnt vmcnt(10)" ::: "memory");
    __builtin_amdgcn_sched_barrier(0);

    f32x4 acc[4];
    #pragma unroll
    for (int g = 0; g < 4; ++g)
      #pragma unroll
      for (int r = 0; r < 4; ++r) acc[g][r] = (float)q[g][r];

    if (t > 0) {
      // own-half MFMA first: overlaps partner-publish -> LLC visibility
      #pragma unroll
      for (int kk = 0; kk < 4; ++kk)
        #pragma unroll
        for (int g = 0; g < 4; ++g)
          acc[g] = __builtin_amdgcn_mfma_f32_16x16x32_f16(a_own[kk], Br[g][kk], acc[g], 0, 0, 0);
    }
    __builtin_amdgcn_sched_barrier(0);

    if (t > 0) {
      // spin: need partner tag == t in all 4 halves (q(t+1) NOT yet issued, so
      // retry vmcnt drains only cheap LLC loads, never the HBM prefetch)
      const uint32_t want = (uint32_t)t << 16;
      uint32_t a0 = (uint32_t)sv0 ^ want, a1 = (uint32_t)(sv0 >> 32) ^ want;
      uint32_t a2 = (uint32_t)sv1 ^ want, a3 = (uint32_t)(sv1 >> 32) ^ want;
      uint32_t mx = a0 > a1 ? a0 : a1;
      mx = mx > a2 ? mx : a2;
      mx = mx > a3 ? mx : a3;
      while (__ballot(mx < 0x10000u) != 0xFFFFFFFFFFFFFFFFull) {
        __builtin_amdgcn_s_sleep(1);
        sv0 = __hip_atomic_load(eb + 0, __ATOMIC_RELAXED, __HIP_MEMORY_SCOPE_AGENT);
        sv1 = __hip_atomic_load(eb + 1, __ATOMIC_RELAXED, __HIP_MEMORY_SCOPE_AGENT);
        a0 = (uint32_t)sv0 ^ want; a1 = (uint32_t)(sv0 >> 32) ^ want;
        a2 = (uint32_t)sv1 ^ want; a3 = (uint32_t)(sv1 >> 32) ^ want;
        mx = a0 > a1 ? a0 : a1;
        mx = mx > a2 ? mx : a2;
        mx = mx > a3 ? mx : a3;
      }
      // stage partner h(t-1) -> LDS[pr] partner half (4 f16 -> one b64)
      u32x2 pk;
      pk[0] = ((uint32_t)sv0 & 0xffffu) | (((uint32_t)(sv0 >> 32)) << 16);
      pk[1] = ((uint32_t)sv1 & 0xffffu) | (((uint32_t)(sv1 >> 32)) << 16);
      *(u32x2*)(smem + HB_OFF + pr + stg_byte) = pk;
    }

    // next-step gx prefetch: issued only after the spin, pinned here
    __builtin_amdgcn_sched_barrier(0);
    {
      int ttn = tt + stp;
      ttn = ttn < 0 ? 0 : (ttn > SEQ - 1 ? SEQ - 1 : ttn);
      issue_q(ttn * 8 + bt);
    }
    __builtin_amdgcn_sched_barrier(0);

    asm volatile("s_waitcnt lgkmcnt(0)" ::: "memory");   // stage visible
    __builtin_amdgcn_sched_barrier(0);
    __builtin_amdgcn_s_barrier();

    if (t > 0) {
      f16x8 a_par[4];
      #pragma unroll
      for (int kk = 0; kk < 4; ++kk) {
        const int byte = ((lp * 512 + (1 - half) * 256 + kk * 64 + lg * 16) ^ ((lp & 7) << 4)) + pr;
        a_par[kk] = *(const f16x8*)(smem + HB_OFF + byte);
      }
      #pragma unroll
      for (int kk = 0; kk < 2; ++kk)
        #pragma unroll
        for (int g = 0; g < 4; ++g)
          acc[g] = __builtin_amdgcn_mfma_f32_16x16x32_f16(a_par[kk], Br[g][4 + kk], acc[g], 0, 0, 0);
      #pragma unroll
      for (int kk = 2; kk < 4; ++kk)
        #pragma unroll
        for (int g = 0; g < 4; ++g) {
          f16x8 bv = *(const f16x8*)(wtb + (g * 2 + (kk - 2)) * 1024 + (size_t)l * 16);
          acc[g] = __builtin_amdgcn_mfma_f32_16x16x32_f16(a_par[kk], bv, acc[g], 0, 0, 0);
        }
    }

    float* outt = outb + (size_t)tt * (128 * 512);
    const int hid_lane = half * 128 + w * 16 + lp;
    #pragma unroll
    for (int r = 0; r < 4; ++r) {
      const float fg = __builtin_amdgcn_rcpf(1.0f + __builtin_amdgcn_exp2f(acc[0][r]));
      const float ig = __builtin_amdgcn_rcpf(1.0f + __builtin_amdgcn_exp2f(acc[1][r]));
      const float cg = 1.0f - 2.0f * __builtin_amdgcn_rcpf(__builtin_amdgcn_exp2f(acc[2][r]) + 1.0f);
      const float og = __builtin_amdgcn_rcpf(1.0f + __builtin_amdgcn_exp2f(acc[3][r]));
      const float cn = fg * cst[r] + ig * cg;
      cst[r] = cn;
      const float th = 1.0f - 2.0f * __builtin_amdgcn_rcpf(__builtin_amdgcn_exp2f(cn * SC_TANH) + 1.0f);
      const float h = og * th;
      const int row = lg * 4 + r;
      const int hbyte = ((row * 512 + hid_lane * 2) ^ ((row & 7) << 4)) + pw;
      *(f16*)(smem + HB_OFF + hbyte) = (f16)h;          // own half -> LDS[pw]
      union { f16 f; uint16_t u; } hb; hb.f = (f16)h;
      __hip_atomic_store(ex_own + (t & 1) * 2048 + pubw + r * 128,
                         ((uint32_t)(t + 1) << 16) | (uint32_t)hb.u,
                         __ATOMIC_RELAXED, __HIP_MEMORY_SCOPE_AGENT);
      outt[vo + r * 512] = h;
    }

    asm volatile("s_waitcnt lgkmcnt(0)" ::: "memory");   // h(t) LDS writes done
    __builtin_amdgcn_sched_barrier(0);
    __builtin_amdgcn_s_barrier();
  }
}

// ---------------- launch -------------------------------------------------------
extern "C" void kernel_launch(void* const* d_in, const int* in_sizes, int n_in,
                              void* d_out, int out_size, void* d_ws, size_t ws_size,
                              hipStream_t stream) {
  (void)in_sizes; (void)n_in; (void)out_size;
  PrepP pp;
  const float* X = (const float*)d_in[0];
  for (int i = 0; i < 8; ++i) {
    pp.W[i]  = (const float*)d_in[1 + 2 * i];
    pp.Bv[i] = (const float*)d_in[2 + 2 * i];
  }
  char* ws = (char*)d_ws;
  pp.wx = (f16*)(ws + WX_OFF);
  pp.bias = (float*)(ws + BIAS_OFF);
  uint32_t* ex = (uint32_t*)(ws + EX_OFF);
  f16* gx = (f16*)(ws + GX_OFF);

  int nd;
  if (ws_size >= (size_t)GX_OFF + 2 * GXD) nd = 2;
  else if (ws_size >= (size_t)GX_OFF + GXD) nd = 1;
  else return;

  hipFuncSetAttribute(reinterpret_cast<const void*>(k_rec),
                      hipFuncAttributeMaxDynamicSharedMemorySize, REC_LDS);

  hipMemsetAsync(ws + EX_OFF, 0, EX_BYTES, stream);
  k_prep<<<dim3(512), dim3(256), 0, stream>>>(pp);

  const int passes = (nd == 2) ? 1 : 2;
  for (int ps = 0; ps < passes; ++ps) {
    const int d0 = (nd == 2) ? 0 : ps;
    GemP gp; gp.X = X; gp.wx = pp.wx; gp.bias = pp.bias; gp.gx = gx; gp.d0 = d0; gp.nd = nd;
    k_gemm<<<dim3(512 * 8 * nd), dim3(256), 0, stream>>>(gp);
    RecP rp;
    for (int i = 0; i < 8; ++i) rp.W[i] = pp.W[i];
    rp.gx = gx; rp.ex = ex; rp.out = (float*)d_out; rp.d0 = d0;
    k_rec<<<dim3(16 * nd), dim3(512), REC_LDS, stream>>>(rp);
  }
}

// Round 11
// 898.752 us; speedup vs baseline: 2.8315x; 1.1592x over previous
//
#include <hip/hip_runtime.h>
#include <stdint.h>

#define SEQ 512
#define BATCH 128
#define INDIM 256
#define HID 256
#define CS 512

typedef _Float16 f16;
typedef __attribute__((ext_vector_type(8))) _Float16 f16x8;
typedef __attribute__((ext_vector_type(4))) _Float16 f16x4;
typedef __attribute__((ext_vector_type(4))) float f32x4;
typedef __attribute__((ext_vector_type(2))) uint32_t u32x2;

// ws layout:
//   [0,1MB)        wx   : [2][1024 n][256 k] f16   (pre-scaled by gate exp2-factor)
//   [1MB,1MB+8KB)  bias : [2048] f32               (pre-scaled)
//   [2MB,2.5MB)    ex   : [dir 2][bt 8][half 2][slot 2][2048] u32 tagged-h
//   [4MB,...)      gx   : per dir 128MB: [mt 4096][half 2][w 8][g 4][lane 64][8B]
#define WX_OFF   0u
#define BIAS_OFF (1u<<20)
#define EX_OFF   (2u<<20)
#define EX_BYTES (2*8*2*2*2048*4)
#define GX_OFF   (4u<<20)
#define GXD ((size_t)4096 * 32768)   // 128MB per dir

// gate scale: y = s_g*(Wz+b); f,i,o: s=-log2e -> sig = rcp(1+exp2(y))
//                              c:    s=+2log2e -> tanh = 1-2*rcp(exp2(y)+1)
#define SC_SIG (-1.4426950408889634f)
#define SC_TANH (2.8853900817779268f)

__device__ __forceinline__ void load_lds16(const void* g, void* l) {
  __builtin_amdgcn_global_load_lds((const __attribute__((address_space(1))) void*)g,
                                   (__attribute__((address_space(3))) void*)l, 16, 0, 0);
}

// ---------------- kernel 1: Wx -> f16 (pre-scaled), bias table -----------------
struct PrepP { const float* W[8]; const float* Bv[8]; f16* wx; float* bias; };

__global__ __launch_bounds__(256) void k_prep(PrepP p) {
  const int u = blockIdx.x * 256 + threadIdx.x;       // 131072 threads exactly
  const int k4 = (u & 63) * 4;
  const int n = (u >> 6) & 1023;
  const int dir = u >> 16;
  const int g = n >> 8;
  const float s = (g == 2) ? SC_TANH : SC_SIG;
  const float* src = p.W[dir * 4 + g] + (size_t)(n & 255) * CS + HID + k4;
  f32x4 a = *(const f32x4*)src;
  f16x4 v;
  #pragma unroll
  for (int j = 0; j < 4; ++j) v[j] = (f16)(a[j] * s);
  *(f16x4*)(p.wx + ((size_t)dir * 1024 + n) * 256 + k4) = v;
  if (u < 2048) {
    const int gg = (u >> 8) & 3;
    const float ss = (gg == 2) ? SC_TANH : SC_SIG;
    p.bias[u] = p.Bv[(u >> 10) * 4 + gg][u & 255] * ss;
  }
}

// ---------------- kernel 2: Gx = X @ Wx^T + b  (f16, split-H layout) ------------
struct GemP { const float* X; const f16* wx; const float* bias; f16* gx; int d0, nd; };

__global__ __launch_bounds__(256) void k_gemm(GemP p) {
  __shared__ float As[128 * 64];   // 32KB, rows 256B, XOR-swizzled
  __shared__ f16   Bs[128 * 64];   // 16KB, rows 128B, XOR-swizzled
  const int tid = threadIdx.x, l = tid & 63, w = tid >> 6;
  const int lp = l & 15, lg = l >> 4;
  const int NB = 8 * p.nd;
  const int nb = blockIdx.x % NB, mb = blockIdx.x / NB;
  const int m0 = mb * 128;
  const int wm = w >> 1, wn = w & 1;

  f32x4 acc[4][4];
  #pragma unroll
  for (int a = 0; a < 4; ++a)
    #pragma unroll
    for (int b = 0; b < 4; ++b) acc[a][b] = (f32x4){0.f, 0.f, 0.f, 0.f};

  auto stage = [&](int kb) {
    #pragma unroll
    for (int j = 0; j < 8; ++j) {
      const int i = w * 8 + j;
      const int rl = i * 4 + lg;
      const int kc = (lp * 16) ^ ((rl & 7) << 4);
      const char* g = (const char*)p.X + ((size_t)(m0 + rl) * 256 + (size_t)kb * 64) * 4 + kc;
      load_lds16(g, (char*)As + i * 1024 + l * 16);
    }
    #pragma unroll
    for (int j = 0; j < 4; ++j) {
      const int i = w * 4 + j;
      const int rl = i * 8 + (l >> 3);
      const int kc = ((l & 7) * 16) ^ ((rl & 7) << 4);
      const char* g = (const char*)p.wx + ((size_t)(p.d0 * 1024 + nb * 128 + rl) * 256 + (size_t)kb * 64) * 2 + kc;
      load_lds16(g, (char*)Bs + i * 1024 + l * 16);
    }
  };

  stage(0);
  for (int kb = 0; kb < 4; ++kb) {
    __syncthreads();
    #pragma unroll
    for (int ks = 0; ks < 2; ++ks) {
      f16x8 af[4];
      #pragma unroll
      for (int mi = 0; mi < 4; ++mi) {
        const int r = wm * 64 + mi * 16 + lp;
        const int kbyte = ks * 128 + lg * 32;
        const int sw = (r & 7) << 4;
        f32x4 a0 = *(const f32x4*)((const char*)As + r * 256 + (kbyte ^ sw));
        f32x4 a1 = *(const f32x4*)((const char*)As + r * 256 + ((kbyte + 16) ^ sw));
        f16x8 v;
        #pragma unroll
        for (int j = 0; j < 4; ++j) { v[j] = (f16)a0[j]; v[4 + j] = (f16)a1[j]; }
        af[mi] = v;
      }
      #pragma unroll
      for (int ni = 0; ni < 4; ++ni) {
        const int rn = wn * 64 + ni * 16 + lp;
        const int kbyte = (ks * 64 + lg * 16) ^ ((rn & 7) << 4);
        f16x8 bf = *(const f16x8*)((const char*)Bs + rn * 128 + kbyte);
        #pragma unroll
        for (int mi = 0; mi < 4; ++mi)
          acc[mi][ni] = __builtin_amdgcn_mfma_f32_16x16x32_f16(af[mi], bf, acc[mi][ni], 0, 0, 0);
      }
    }
    if (kb < 3) { __syncthreads(); stage(kb + 1); }
  }

  // epilogue: +bias, f16, store in split-H k_rec layout (consumer lane == l)
  #pragma unroll
  for (int ni = 0; ni < 4; ++ni) {
    const int n_all = nb * 128 + wn * 64 + ni * 16 + lp;
    const float bv = p.bias[p.d0 * 1024 + n_all];
    const int gdl = n_all >> 10;
    const int n = n_all & 1023;
    const int g = n >> 8, hid = n & 255;
    const int half = hid >> 7, w8 = (hid >> 4) & 7;
    #pragma unroll
    for (int mi = 0; mi < 4; ++mi) {
      const int mt = (m0 + wm * 64 + mi * 16) >> 4;
      f16x4 h4;
      #pragma unroll
      for (int r = 0; r < 4; ++r) h4[r] = (f16)(acc[mi][ni][r] + bv);
      char* dst = (char*)p.gx + (size_t)gdl * GXD
                + ((((size_t)mt * 2 + half) * 8 + w8) * 4 + g) * 512 + (size_t)l * 8;
      *(f16x4*)dst = h4;
    }
  }
}

// ---------------- kernel 3: split-H recurrence, 2 blocks per group -------------
// LDS: [0,16384)       h: 2 buffers x (16 rows x 256 hid f16), byte ^= (row&7)<<4
//      [16384,81920)   wt: wave w at 16384+w*8192, 8 frags (g x kk{2,3} partner)
#define HB_OFF 0
#define WT_OFF 16384
#define REC_LDS 81920

struct RecP { const float* W[8]; const f16* gx; uint32_t* ex; float* out; int d0; };

__global__ __launch_bounds__(512, 2) void k_rec(RecP p) {
  extern __shared__ char smem[];
  const int tid = threadIdx.x, l = tid & 63, w = tid >> 6;   // w 0..7
  const int lp = l & 15, lg = l >> 4;
  const int bx = blockIdx.x;
  const int bt = bx & 7;
  const int half = (bx >> 3) & 1;          // partner block = bx ^ 8 (same XCD)
  const int dirl = bx >> 4;
  const int dir = p.d0 + dirl;

  char* wtb = smem + WT_OFF + w * 8192;
  const char* gxd = (const char*)p.gx + (size_t)dirl * GXD;

  // ---- weights: own-k-first index: Br[g][i], i<4: k=half*128+i*32 (own h half),
  //      i>=4: k=(1-half)*128+(i-4)*32 (partner). i=6,7 live in LDS. ----
  f16x8 Br[4][6];
  #pragma unroll
  for (int g = 0; g < 4; ++g) {
    const float s = (g == 2) ? SC_TANH : SC_SIG;
    const float* wrow = p.W[dir * 4 + g] + (size_t)(half * 128 + w * 16 + lp) * CS;
    #pragma unroll
    for (int i = 0; i < 8; ++i) {
      const int kb = (i < 4 ? half * 128 + i * 32 : (1 - half) * 128 + (i - 4) * 32) + lg * 8;
      f32x4 a0 = *(const f32x4*)(wrow + kb);
      f32x4 a1 = *(const f32x4*)(wrow + kb + 4);
      f16x8 v;
      #pragma unroll
      for (int j = 0; j < 4; ++j) { v[j] = (f16)(a0[j] * s); v[4 + j] = (f16)(a1[j] * s); }
      if (i >= 6) *(f16x8*)(wtb + (g * 2 + (i - 6)) * 1024 + (size_t)l * 16) = v;
      else Br[g][i] = v;
    }
  }

  float cst[4];
  #pragma unroll
  for (int r = 0; r < 4; ++r) cst[r] = 0.f;

  int tt = dir ? (SEQ - 1) : 0;
  const int stp = dir ? -1 : 1;

  // ex: [dir][bt][half][slot][2048 u32]
  uint32_t* exg = p.ex + (size_t)(dir * 8 + bt) * (2 * 2 * 2048);
  uint32_t* ex_own = exg + half * 2 * 2048;
  const uint32_t* ex_par = exg + (1 - half) * 2 * 2048;
  const int pubw = (lg * 4) * 128 + w * 16 + lp;          // + r*128
  // partner staging: thread stages words u=tid*4..+3 -> LDS row u>>7, col (u&127)
  const int stg_row = tid >> 5;
  const int stg_byte = (stg_row * 512 + ((1 - half) * 128 + ((tid * 4) & 127)) * 2)
                       ^ ((stg_row & 7) << 4);

  float* outb = p.out + ((size_t)(bt * 16) * 512 + (size_t)dir * 256 + half * 128 + w * 16);
  const int vo = (lg * 4) * 512 + lp;                      // + r*512

  // gx prefetch: f16x4 per gate (this wave's 16-hid slice, 4 batch rows)
  f16x4 q[4];
  auto issue_q = [&](int mt) {
    const char* s = gxd + (((size_t)mt * 2 + half) * 8 + w) * 2048 + (size_t)l * 8;
    #pragma unroll
    for (int g = 0; g < 4; ++g)
      q[g] = *(const f16x4*)(s + g * 512);
  };

  issue_q(tt * 8 + bt);
  asm volatile("s_waitcnt vmcnt(0) lgkmcnt(0)" ::: "memory");
  __builtin_amdgcn_sched_barrier(0);
  __builtin_amdgcn_s_barrier();

  for (int t = 0; t < SEQ; ++t, tt += stp) {
    const int pr = ((t & 1) ^ 1) * 8192;   // h(t-1) buffer
    const int pw = (t & 1) * 8192;         // h(t) buffer

    // spec loads for partner tag t (slot (t-1)&1): issued FIRST, checked after
    // own-MFMA (~400cy later) so LLC visibility latency is hidden.
    uint64_t sv0, sv1;
    const uint64_t* eb = (const uint64_t*)(ex_par + ((t - 1) & 1) * 2048) + tid * 2;
    sv0 = __hip_atomic_load(eb + 0, __ATOMIC_RELAXED, __HIP_MEMORY_SCOPE_AGENT);
    sv1 = __hip_atomic_load(eb + 1, __ATOMIC_RELAXED, __HIP_MEMORY_SCOPE_AGENT);
    __builtin_amdgcn_sched_barrier(0);

    // own-half a-frags (k reindexed: own = half*128 + kk*32)
    f16x8 a_own[4];
    #pragma unroll
    for (int kk = 0; kk < 4; ++kk) {
      const int byte = ((lp * 512 + half * 256 + kk * 64 + lg * 16) ^ ((lp & 7) << 4)) + pr;
      a_own[kk] = *(const f16x8*)(smem + HB_OFF + byte);
    }
    // q(t) retired: ops newer than q(t) = [4 pub][4 out][2 spec] = 10
    asm volatile("s_waitcnt vmcnt(10)" ::: "memory");
    __builtin_amdgcn_sched_barrier(0);

    f32x4 acc[4];
    #pragma unroll
    for (int g = 0; g < 4; ++g)
      #pragma unroll
      for (int r = 0; r < 4; ++r) acc[g][r] = (float)q[g][r];

    if (t > 0) {
      // own-half MFMA first: overlaps partner-publish -> LLC visibility
      #pragma unroll
      for (int kk = 0; kk < 4; ++kk)
        #pragma unroll
        for (int g = 0; g < 4; ++g)
          acc[g] = __builtin_amdgcn_mfma_f32_16x16x32_f16(a_own[kk], Br[g][kk], acc[g], 0, 0, 0);
    }
    __builtin_amdgcn_sched_barrier(0);

    if (t > 0) {
      // spin: need partner tag == t in all 4 halves (q(t+1) NOT yet issued, so
      // retry vmcnt drains only cheap LLC loads, never the HBM prefetch).
      // No sleep: retry period = LLC load latency, samples freshest data.
      const uint32_t want = (uint32_t)t << 16;
      uint32_t a0 = (uint32_t)sv0 ^ want, a1 = (uint32_t)(sv0 >> 32) ^ want;
      uint32_t a2 = (uint32_t)sv1 ^ want, a3 = (uint32_t)(sv1 >> 32) ^ want;
      uint32_t mx = a0 > a1 ? a0 : a1;
      mx = mx > a2 ? mx : a2;
      mx = mx > a3 ? mx : a3;
      while (__ballot(mx < 0x10000u) != 0xFFFFFFFFFFFFFFFFull) {
        sv0 = __hip_atomic_load(eb + 0, __ATOMIC_RELAXED, __HIP_MEMORY_SCOPE_AGENT);
        sv1 = __hip_atomic_load(eb + 1, __ATOMIC_RELAXED, __HIP_MEMORY_SCOPE_AGENT);
        a0 = (uint32_t)sv0 ^ want; a1 = (uint32_t)(sv0 >> 32) ^ want;
        a2 = (uint32_t)sv1 ^ want; a3 = (uint32_t)(sv1 >> 32) ^ want;
        mx = a0 > a1 ? a0 : a1;
        mx = mx > a2 ? mx : a2;
        mx = mx > a3 ? mx : a3;
      }
      // past the spin: prioritize this wave's critical section (T5)
      __builtin_amdgcn_s_setprio(1);
      // stage partner h(t-1) -> LDS[pr] partner half (4 f16 -> one b64)
      u32x2 pk;
      pk[0] = ((uint32_t)sv0 & 0xffffu) | (((uint32_t)(sv0 >> 32)) << 16);
      pk[1] = ((uint32_t)sv1 & 0xffffu) | (((uint32_t)(sv1 >> 32)) << 16);
      *(u32x2*)(smem + HB_OFF + pr + stg_byte) = pk;
    }

    // next-step gx prefetch: issued only after the spin, pinned here
    __builtin_amdgcn_sched_barrier(0);
    {
      int ttn = tt + stp;
      ttn = ttn < 0 ? 0 : (ttn > SEQ - 1 ? SEQ - 1 : ttn);
      issue_q(ttn * 8 + bt);
    }
    __builtin_amdgcn_sched_barrier(0);

    asm volatile("s_waitcnt lgkmcnt(0)" ::: "memory");   // stage visible
    __builtin_amdgcn_sched_barrier(0);
    __builtin_amdgcn_s_barrier();

    if (t > 0) {
      f16x8 a_par[4];
      #pragma unroll
      for (int kk = 0; kk < 4; ++kk) {
        const int byte = ((lp * 512 + (1 - half) * 256 + kk * 64 + lg * 16) ^ ((lp & 7) << 4)) + pr;
        a_par[kk] = *(const f16x8*)(smem + HB_OFF + byte);
      }
      #pragma unroll
      for (int kk = 0; kk < 2; ++kk)
        #pragma unroll
        for (int g = 0; g < 4; ++g)
          acc[g] = __builtin_amdgcn_mfma_f32_16x16x32_f16(a_par[kk], Br[g][4 + kk], acc[g], 0, 0, 0);
      #pragma unroll
      for (int kk = 2; kk < 4; ++kk)
        #pragma unroll
        for (int g = 0; g < 4; ++g) {
          f16x8 bv = *(const f16x8*)(wtb + (g * 2 + (kk - 2)) * 1024 + (size_t)l * 16);
          acc[g] = __builtin_amdgcn_mfma_f32_16x16x32_f16(a_par[kk], bv, acc[g], 0, 0, 0);
        }
    }

    // gates: compute all h first (regs), then publish ASAP, then LDS/out
    float hv[4];
    #pragma unroll
    for (int r = 0; r < 4; ++r) {
      const float fg = __builtin_amdgcn_rcpf(1.0f + __builtin_amdgcn_exp2f(acc[0][r]));
      const float ig = __builtin_amdgcn_rcpf(1.0f + __builtin_amdgcn_exp2f(acc[1][r]));
      const float cg = 1.0f - 2.0f * __builtin_amdgcn_rcpf(__builtin_amdgcn_exp2f(acc[2][r]) + 1.0f);
      const float og = __builtin_amdgcn_rcpf(1.0f + __builtin_amdgcn_exp2f(acc[3][r]));
      const float cn = fg * cst[r] + ig * cg;
      cst[r] = cn;
      const float th = 1.0f - 2.0f * __builtin_amdgcn_rcpf(__builtin_amdgcn_exp2f(cn * SC_TANH) + 1.0f);
      hv[r] = og * th;
    }
    // publish first: ex visibility is the inter-block critical path
    #pragma unroll
    for (int r = 0; r < 4; ++r) {
      union { f16 f; uint16_t u; } hb; hb.f = (f16)hv[r];
      __hip_atomic_store(ex_own + (t & 1) * 2048 + pubw + r * 128,
                         ((uint32_t)(t + 1) << 16) | (uint32_t)hb.u,
                         __ATOMIC_RELAXED, __HIP_MEMORY_SCOPE_AGENT);
    }
    __builtin_amdgcn_s_setprio(0);
    const int hid_lane = half * 128 + w * 16 + lp;
    #pragma unroll
    for (int r = 0; r < 4; ++r) {
      const int row = lg * 4 + r;
      const int hbyte = ((row * 512 + hid_lane * 2) ^ ((row & 7) << 4)) + pw;
      *(f16*)(smem + HB_OFF + hbyte) = (f16)hv[r];      // own half -> LDS[pw]
    }
    float* outt = outb + (size_t)tt * (128 * 512);
    #pragma unroll
    for (int r = 0; r < 4; ++r)
      outt[vo + r * 512] = hv[r];

    asm volatile("s_waitcnt lgkmcnt(0)" ::: "memory");   // h(t) LDS writes done
    __builtin_amdgcn_sched_barrier(0);
    __builtin_amdgcn_s_barrier();
  }
}

// ---------------- launch -------------------------------------------------------
extern "C" void kernel_launch(void* const* d_in, const int* in_sizes, int n_in,
                              void* d_out, int out_size, void* d_ws, size_t ws_size,
                              hipStream_t stream) {
  (void)in_sizes; (void)n_in; (void)out_size;
  PrepP pp;
  const float* X = (const float*)d_in[0];
  for (int i = 0; i < 8; ++i) {
    pp.W[i]  = (const float*)d_in[1 + 2 * i];
    pp.Bv[i] = (const float*)d_in[2 + 2 * i];
  }
  char* ws = (char*)d_ws;
  pp.wx = (f16*)(ws + WX_OFF);
  pp.bias = (float*)(ws + BIAS_OFF);
  uint32_t* ex = (uint32_t*)(ws + EX_OFF);
  f16* gx = (f16*)(ws + GX_OFF);

  int nd;
  if (ws_size >= (size_t)GX_OFF + 2 * GXD) nd = 2;
  else if (ws_size >= (size_t)GX_OFF + GXD) nd = 1;
  else return;

  hipFuncSetAttribute(reinterpret_cast<const void*>(k_rec),
                      hipFuncAttributeMaxDynamicSharedMemorySize, REC_LDS);

  hipMemsetAsync(ws + EX_OFF, 0, EX_BYTES, stream);
  k_prep<<<dim3(512), dim3(256), 0, stream>>>(pp);

  const int passes = (nd == 2) ? 1 : 2;
  for (int ps = 0; ps < passes; ++ps) {
    const int d0 = (nd == 2) ? 0 : ps;
    GemP gp; gp.X = X; gp.wx = pp.wx; gp.bias = pp.bias; gp.gx = gx; gp.d0 = d0; gp.nd = nd;
    k_gemm<<<dim3(512 * 8 * nd), dim3(256), 0, stream>>>(gp);
    RecP rp;
    for (int i = 0; i < 8; ++i) rp.W[i] = pp.W[i];
    rp.gx = gx; rp.ex = ex; rp.out = (float*)d_out; rp.d0 = d0;
    k_rec<<<dim3(16 * nd), dim3(512), REC_LDS, stream>>>(rp);
  }
}